// Round 11
// baseline (2486.679 us; speedup 1.0000x reference)
//
#include <hip/hip_runtime.h>
#include <hip/hip_bf16.h>
#include <math.h>

#define DM 768
#define DI 1536
#define DSN 16
#define NB 2
#define SL 1024
#define MROWS 2048
#define VOC 50257
#define VOCP 50432           // padded to multiple of 256 for the 256^2 lm_head GEMM
#define EPSR 1e-5f

typedef __attribute__((ext_vector_type(8))) short short8;
typedef __attribute__((ext_vector_type(4))) float f32x4;
typedef __attribute__((ext_vector_type(4))) unsigned short us4;
typedef unsigned short u16;

__device__ inline u16 f2bf(float f) {
    unsigned u = __builtin_bit_cast(unsigned, f);
    u += 0x7FFFu + ((u >> 16) & 1u);   // round-to-nearest-even
    return (u16)(u >> 16);
}

#define G_LDS16(g, l) __builtin_amdgcn_global_load_lds( \
    (const __attribute__((address_space(1))) void*)(g), \
    (__attribute__((address_space(3))) void*)(l), 16, 0, 0)

// ---------------- embedding gather + layer-0 RMSNorm (fused) ----------------
__global__ __launch_bounds__(256)
void k_embed_rms(const int* __restrict__ tok, const float* __restrict__ emb,
                 const float* __restrict__ w, float* __restrict__ x,
                 u16* __restrict__ out) {
    int r = blockIdx.x;
    int t = tok[r];
    const float* src = emb + (size_t)t * DM;
    int c0 = threadIdx.x * 3;
    float v[3]; float ss = 0.f;
#pragma unroll
    for (int i = 0; i < 3; ++i) {
        v[i] = src[c0 + i]; ss += v[i] * v[i];
        x[(size_t)r * DM + c0 + i] = v[i];
    }
#pragma unroll
    for (int o = 32; o > 0; o >>= 1) ss += __shfl_down(ss, o);
    __shared__ float s[4];
    int lane = threadIdx.x & 63, wv = threadIdx.x >> 6;
    if (lane == 0) s[wv] = ss;
    __syncthreads();
    float sc = rsqrtf((s[0] + s[1] + s[2] + s[3]) / (float)DM + EPSR);
#pragma unroll
    for (int i = 0; i < 3; ++i)
        out[(size_t)r * DM + c0 + i] = f2bf(v[i] * sc * w[c0 + i]);
}

// ---------------- RMSNorm -> bf16 ----------------
__global__ __launch_bounds__(256)
void k_rmsnorm_bf16(const float* __restrict__ x, const float* __restrict__ w,
                    u16* __restrict__ out) {
    int r = blockIdx.x;
    const float* row = x + (size_t)r * DM;
    int c0 = threadIdx.x * 3;
    float v[3]; float ss = 0.f;
#pragma unroll
    for (int i = 0; i < 3; ++i) { v[i] = row[c0 + i]; ss += v[i] * v[i]; }
#pragma unroll
    for (int o = 32; o > 0; o >>= 1) ss += __shfl_down(ss, o);
    __shared__ float s[4];
    int lane = threadIdx.x & 63, wv = threadIdx.x >> 6;
    if (lane == 0) s[wv] = ss;
    __syncthreads();
    float sc = rsqrtf((s[0] + s[1] + s[2] + s[3]) / (float)DM + EPSR);
#pragma unroll
    for (int i = 0; i < 3; ++i)
        out[(size_t)r * DM + c0 + i] = f2bf(v[i] * sc * w[c0 + i]);
}

// -------- fused multi-segment f32 -> bf16 weight conversion (one launch) --------
struct CvtSeg { const float* src; u16* dst; int sr, sc, sld, dc, blk0, total4; };
struct CvtArgs { CvtSeg seg[9]; };

__global__ __launch_bounds__(256)
void k_cvt_multi(CvtArgs a) {
    int b = blockIdx.x;
    int s = 0;
#pragma unroll
    for (int q = 1; q < 9; ++q) if (a.seg[q].blk0 <= b) s = q;
    const CvtSeg& g = a.seg[s];
    long i4 = (long)(b - g.blk0) * 256 + threadIdx.x;
    if (i4 >= g.total4) return;
    long i = i4 * 4;
    int r = (int)(i / g.dc), c0 = (int)(i % g.dc);
    us4 o;
#pragma unroll
    for (int e = 0; e < 4; ++e) {
        int c = c0 + e;
        float v = (r < g.sr && c < g.sc) ? g.src[(size_t)r * g.sld + c] : 0.f;
        o[e] = f2bf(v);
    }
    *(us4*)&g.dst[i] = o;
}

// ---------------- f32 -> bf16 with 2D pad, 4 elems/thread (dc % 4 == 0) ----------------
__global__ void k_cvt_pad4(const float* __restrict__ src, u16* __restrict__ dst,
                           int sr, int sc, int sld, int dc, long total4) {
    long i4 = (long)blockIdx.x * 256 + threadIdx.x;
    if (i4 >= total4) return;
    long i = i4 * 4;
    int r = (int)(i / dc), c0 = (int)(i % dc);
    us4 o;
#pragma unroll
    for (int e = 0; e < 4; ++e) {
        int c = c0 + e;
        float v = (r < sr && c < sc) ? src[(size_t)r * sld + c] : 0.f;
        o[e] = f2bf(v);
    }
    *(us4*)&dst[i] = o;
}

// ---------------- causal depthwise conv (width 4) + bias + silu ----------------
__global__ void k_conv_silu(const float* __restrict__ xz, const float* __restrict__ cw,
                            const float* __restrict__ cb, float* __restrict__ uc,
                            u16* __restrict__ ucb) {
    int d = blockIdx.x * 256 + threadIdx.x;   // 0..1535
    int r = blockIdx.y;                       // 0..2047
    int l = r & (SL - 1);
    float acc = cb[d];
#pragma unroll
    for (int j = 0; j < 4; ++j) {
        int ls = l - 3 + j;
        if (ls >= 0) acc += xz[(size_t)(r - 3 + j) * (2 * DI) + d] * cw[d * 4 + j];
    }
    float s = acc / (1.f + __expf(-acc));
    uc[(size_t)r * DI + d] = s;
    ucb[(size_t)r * DI + d] = f2bf(s);
}

// ---------------- chunked selective scan (8 chunks x 128 steps, 1 kernel) --------------
__global__ __launch_bounds__(512)
void k_scan2(const float* __restrict__ delta, const float* __restrict__ uc,
             const float* __restrict__ xdbl, const float* __restrict__ xz,
             const float* __restrict__ alog, const float* __restrict__ Dp,
             u16* __restrict__ ybf) {
    __shared__ float ds2[8][16][20], us2[8][16][20], bn2[8][16][20], cn2[8][16][20];
    __shared__ float Sm[8][16][16], Pm[8][16][16];
    int b  = blockIdx.x / 96;
    int d0 = (blockIdx.x % 96) * 16;
    int tid = threadIdx.x, w = tid >> 6, lane = tid & 63;
    int ch = lane >> 2, nq = lane & 3;
    int d = d0 + ch;
    float A[4];
#pragma unroll
    for (int k = 0; k < 4; ++k) A[k] = -__expf(alog[d * DSN + nq + 4 * k]);
    int tb = w * 128;

    // ---- phase 1 ----
    float h[4] = {0.f, 0.f, 0.f, 0.f};
    float sdl = 0.f;
    for (int t0 = 0; t0 < 128; t0 += 16) {
        int row0 = b * SL + tb + t0;
#pragma unroll
        for (int i = 0; i < 4; ++i) {
            int lin = i * 64 + lane, tt = lin >> 4, cc = lin & 15;
            size_t row = (size_t)(row0 + tt);
            ds2[w][cc][tt] = delta[row * DI + d0 + cc];
            us2[w][cc][tt] = uc[row * DI + d0 + cc];
            bn2[w][cc][tt] = xdbl[row * 128 + 48 + cc];
        }
#pragma unroll
        for (int g4 = 0; g4 < 4; ++g4) {
            f32x4 dl = *(const f32x4*)&ds2[w][ch][g4 * 4];
            f32x4 uv = *(const f32x4*)&us2[w][ch][g4 * 4];
            f32x4 bv[4];
#pragma unroll
            for (int k = 0; k < 4; ++k) bv[k] = *(const f32x4*)&bn2[w][nq + 4 * k][g4 * 4];
#pragma unroll
            for (int s = 0; s < 4; ++s) {
                float du = dl[s] * uv[s];
                sdl += dl[s];
#pragma unroll
                for (int k = 0; k < 4; ++k) {
                    float dA = __expf(dl[s] * A[k]);
                    h[k] = h[k] * dA + du * bv[k][s];
                }
            }
        }
    }
#pragma unroll
    for (int k = 0; k < 4; ++k) {
        Sm[w][ch][nq + 4 * k] = h[k];
        Pm[w][ch][nq + 4 * k] = __expf(A[k] * sdl);
    }
    __syncthreads();
    if (tid < 256) {
        int c2 = tid >> 4, n2 = tid & 15;
        float H = 0.f;
#pragma unroll
        for (int g = 0; g < 8; ++g) {
            float hi = H;
            H = Pm[g][c2][n2] * H + Sm[g][c2][n2];
            Sm[g][c2][n2] = hi;
        }
    }
    __syncthreads();
    // ---- phase 3 ----
    float Dv = Dp[d];
#pragma unroll
    for (int k = 0; k < 4; ++k) h[k] = Sm[w][ch][nq + 4 * k];
    for (int t0 = 0; t0 < 128; t0 += 16) {
        int row0 = b * SL + tb + t0;
#pragma unroll
        for (int i = 0; i < 4; ++i) {
            int lin = i * 64 + lane, tt = lin >> 4, cc = lin & 15;
            size_t row = (size_t)(row0 + tt);
            ds2[w][cc][tt] = delta[row * DI + d0 + cc];
            us2[w][cc][tt] = uc[row * DI + d0 + cc];
            bn2[w][cc][tt] = xdbl[row * 128 + 48 + cc];
            cn2[w][cc][tt] = xdbl[row * 128 + 64 + cc];
        }
#pragma unroll
        for (int g4 = 0; g4 < 4; ++g4) {
            f32x4 dl = *(const f32x4*)&ds2[w][ch][g4 * 4];
            f32x4 uv = *(const f32x4*)&us2[w][ch][g4 * 4];
            f32x4 bv[4], cv[4];
#pragma unroll
            for (int k = 0; k < 4; ++k) {
                bv[k] = *(const f32x4*)&bn2[w][nq + 4 * k][g4 * 4];
                cv[k] = *(const f32x4*)&cn2[w][nq + 4 * k][g4 * 4];
            }
#pragma unroll
            for (int s = 0; s < 4; ++s) {
                float du = dl[s] * uv[s];
                float p = 0.f;
#pragma unroll
                for (int k = 0; k < 4; ++k) {
                    float dA = __expf(dl[s] * A[k]);
                    h[k] = h[k] * dA + du * bv[k][s];
                    p += h[k] * cv[k][s];
                }
                p += __shfl_xor(p, 1);
                p += __shfl_xor(p, 2);
                if (nq == 0) {
                    size_t row = (size_t)(row0 + g4 * 4 + s);
                    float z = xz[row * (2 * DI) + DI + d];
                    float y = p + uv[s] * Dv;
                    y *= z / (1.f + __expf(-z));
                    ybf[row * DI + d] = f2bf(y);
                }
            }
        }
    }
}

// ------- 128^2 bf16 MFMA GEMM (layer GEMMs), fused epilogue --------
// EPIL: 0 = plain, 1 = add residual, 2 = softplus(v + bias[col])
template <int EPIL>
__global__ __launch_bounds__(256)
void k_gemm_bt(const u16* __restrict__ A, const u16* __restrict__ W,
               float* C, const float* RES,
               const float* __restrict__ BIASV,
               int K, int ldc, int nTm) {
    __shared__ u16 Al[128 * 32];
    __shared__ u16 Wl[128 * 32];
    int nwg = gridDim.x;
    int qc = nwg >> 3, rc = nwg & 7;
    int xcd = blockIdx.x & 7, j = blockIdx.x >> 3;
    int wg = (xcd < rc ? xcd * (qc + 1) : rc * (qc + 1) + (xcd - rc) * qc) + j;
    int m0 = (wg % nTm) * 128, n0 = (wg / nTm) * 128;

    int tid = threadIdx.x, wave = tid >> 6, lane = tid & 63;
    int wm = wave >> 1, wn = wave & 1;
    f32x4 acc[4][4] = {};
    const int rS = (lane >> 2);
    const int kS = (((lane & 3) ^ ((lane >> 3) & 3)) * 8);
    const int kofs = (((lane >> 4) ^ ((lane >> 1) & 3)) * 8);
    const int fr = lane & 15;

    for (int k0 = 0; k0 < K; k0 += 32) {
#pragma unroll
        for (int i = 0; i < 2; ++i) {
            int rowA = m0 + wave * 32 + i * 16 + rS;
            G_LDS16(A + (size_t)rowA * K + k0 + kS, &Al[wave * 1024 + i * 512]);
            int rowW = n0 + wave * 32 + i * 16 + rS;
            G_LDS16(W + (size_t)rowW * K + k0 + kS, &Wl[wave * 1024 + i * 512]);
        }
        __syncthreads();
        short8 af[4], bfr[4];
#pragma unroll
        for (int f = 0; f < 4; ++f) {
            af[f]  = *(const short8*)&Al[(wm * 64 + f * 16 + fr) * 32 + kofs];
            bfr[f] = *(const short8*)&Wl[(wn * 64 + f * 16 + fr) * 32 + kofs];
        }
#pragma unroll
        for (int i = 0; i < 4; ++i)
#pragma unroll
            for (int jj = 0; jj < 4; ++jj)
                acc[i][jj] = __builtin_amdgcn_mfma_f32_16x16x32_bf16(af[i], bfr[jj], acc[i][jj], 0, 0, 0);
        __syncthreads();
    }
    int r4 = (lane >> 4) * 4;
#pragma unroll
    for (int i = 0; i < 4; ++i)
#pragma unroll
        for (int jj = 0; jj < 4; ++jj) {
            int col = n0 + wn * 64 + jj * 16 + fr;
            float bia = (EPIL == 2) ? BIASV[col] : 0.f;
#pragma unroll
            for (int rr = 0; rr < 4; ++rr) {
                int row = m0 + wm * 64 + i * 16 + r4 + rr;
                size_t off = (size_t)row * ldc + col;
                float v = acc[i][jj][rr];
                if (EPIL == 1) v += RES[off];
                if (EPIL == 2) { v += bia; v = (v > 20.f) ? v : log1pf(__expf(v)); }
                C[off] = v;
            }
        }
}

// ===== 256^2 8-phase bf16 GEMM (lm_head), BK=32 / 64 KiB LDS / 2 blocks-per-CU =====
// 512 thr = 8 waves (2M x 4N); per-wave 128x64 C; counted vmcnt(3) (1 load/half-tile);
// LDS [buf][A/B][half][128x32] with the PROVEN 128^2 swizzle pair (0-conflict layout).
#define BAR  __builtin_amdgcn_s_barrier()
#define LGK0 do { asm volatile("s_waitcnt lgkmcnt(0)" ::: "memory"); \
                  __builtin_amdgcn_sched_barrier(0); } while (0)
#define VMC3 asm volatile("s_waitcnt vmcnt(3)" ::: "memory")
#define VMC0 asm volatile("s_waitcnt vmcnt(0)" ::: "memory")

// stage half-tile (t, op, half): 8 KB; each wave ONE global_load_lds of 1 KB (16 rows x 32)
#define STAGE1(t, op, half, GB, RB) do {                                      \
    const u16* _g = (GB) + (size_t)((RB) + (half) * 128 + (w << 4) + srow) * K \
                    + (t) * 32 + scol;                                         \
    G_LDS16(_g, &lds[(t) & 1][op][half][w << 9]);                              \
} while (0)

#define RDA(dst, t, mq) do {                                                   \
    _Pragma("unroll") for (int _m = 0; _m < 4; ++_m)                           \
        dst[_m] = *(const short8*)&lds[(t) & 1][0][wm]                         \
            [((mq) * 64 + _m * 16 + fr) * 32 + rd_sw];                         \
} while (0)

#define RDB(t, nq) do {                                                       \
    _Pragma("unroll") for (int _n = 0; _n < 2; ++_n)                           \
        bfv[_n] = *(const short8*)&lds[(t) & 1][1][wbh]                        \
            [(wbr * 64 + (nq) * 32 + _n * 16 + fr) * 32 + rd_sw];              \
} while (0)

#define MM8(AF, mq, nq) do {                                                  \
    __builtin_amdgcn_s_setprio(1);                                            \
    _Pragma("unroll") for (int _m = 0; _m < 4; ++_m)                           \
    _Pragma("unroll") for (int _n = 0; _n < 2; ++_n)                           \
        acc[(mq) * 4 + _m][(nq) * 2 + _n] =                                    \
            __builtin_amdgcn_mfma_f32_16x16x32_bf16(                           \
                AF[_m], bfv[_n], acc[(mq) * 4 + _m][(nq) * 2 + _n], 0, 0, 0);  \
    __builtin_amdgcn_s_setprio(0);                                            \
} while (0)

template <int K>
__global__ __launch_bounds__(512, 4)
void k_gemm256(const u16* __restrict__ Ap, const u16* __restrict__ Wp,
               float* __restrict__ C, int ldc, int nmax, int nTm) {
    constexpr int NT = K / 32;       // 24 K-tiles (even, >= 4)
    constexpr int NI = NT / 2;       // 12 pair iterations
    __shared__ __align__(16) u16 lds[2][2][2][4096];  // 64 KiB: [buf][A/B][half][128x32]

    int per8 = gridDim.x >> 3;
    int wg = (blockIdx.x & 7) * per8 + (blockIdx.x >> 3);
    int m0 = (wg % nTm) * 256, n0 = (wg / nTm) * 256;

    int tid = threadIdx.x, w = tid >> 6, lane = tid & 63;
    int wm = w >> 2, wn = w & 3, wbh = wn >> 1, wbr = wn & 1;
    int fr = lane & 15;
    // proven 128^2 swizzle pair for [row][32] layout (64B row stride):
    int rd_sw = (((lane >> 4) ^ ((lane >> 1) & 3)) * 8);   // read col offset (elems)
    int srow  = lane >> 2;                                 // staging row 0..15
    int scol  = (((lane & 3) ^ ((lane >> 3) & 3)) * 8);    // pre-swizzled source col

    f32x4 acc[8][4] = {};
    short8 af0[4], af1[4], bfv[2];

    // ---- prologue: tile0 full + tile1 {A0,A1,B0}; 7 loads/wave; vmcnt(3) => tile0 ----
    STAGE1(0, 0, 0, Ap, m0); STAGE1(0, 0, 1, Ap, m0);
    STAGE1(0, 1, 0, Wp, n0); STAGE1(0, 1, 1, Wp, n0);
    STAGE1(1, 0, 0, Ap, m0); STAGE1(1, 0, 1, Ap, m0);
    STAGE1(1, 1, 0, Wp, n0);
    VMC3; BAR;

    // ---- main loop: vmcnt(3) at phases 4 & 8 (3 half-tiles in flight) ----
    for (int i = 0; i < NI - 1; ++i) {
        const int ta = 2 * i, tb = 2 * i + 1;
        // P1
        RDA(af0, ta, 0); RDB(ta, 0);
        STAGE1(tb, 1, 1, Wp, n0);
        BAR; LGK0; MM8(af0, 0, 0); BAR;
        // P2
        RDA(af1, ta, 1);
        STAGE1(ta + 2, 0, 0, Ap, m0);
        BAR; LGK0; MM8(af1, 1, 0); BAR;
        // P3
        RDB(ta, 1);
        STAGE1(ta + 2, 0, 1, Ap, m0);
        BAR; LGK0; MM8(af1, 1, 1); BAR;
        // P4
        STAGE1(ta + 2, 1, 0, Wp, n0);
        BAR; MM8(af0, 0, 1); VMC3; BAR;
        // P5
        RDA(af0, tb, 0); RDB(tb, 0);
        STAGE1(ta + 2, 1, 1, Wp, n0);
        BAR; LGK0; MM8(af0, 0, 0); BAR;
        // P6
        RDA(af1, tb, 1);
        STAGE1(ta + 3, 0, 0, Ap, m0);
        BAR; LGK0; MM8(af1, 1, 0); BAR;
        // P7
        RDB(tb, 1);
        STAGE1(ta + 3, 0, 1, Ap, m0);
        BAR; LGK0; MM8(af1, 1, 1); BAR;
        // P8
        STAGE1(ta + 3, 1, 0, Wp, n0);
        BAR; MM8(af0, 0, 1); VMC3; BAR;
    }
    // ---- peeled last pair: only P1 stages; vmcnt(0) at P4 ----
    {
        const int ta = NT - 2, tb = NT - 1;
        RDA(af0, ta, 0); RDB(ta, 0);
        STAGE1(tb, 1, 1, Wp, n0);
        BAR; LGK0; MM8(af0, 0, 0); BAR;
        RDA(af1, ta, 1);
        BAR; LGK0; MM8(af1, 1, 0); BAR;
        RDB(ta, 1);
        BAR; LGK0; MM8(af1, 1, 1); BAR;
        BAR; MM8(af0, 0, 1); VMC0; BAR;
        RDA(af0, tb, 0); RDB(tb, 0);
        BAR; LGK0; MM8(af0, 0, 0); BAR;
        RDA(af1, tb, 1);
        BAR; LGK0; MM8(af1, 1, 0); BAR;
        RDB(tb, 1);
        BAR; LGK0; MM8(af1, 1, 1); BAR;
        BAR; MM8(af0, 0, 1); BAR;
    }

    // ---- epilogue: C write (registers only); overlaps the co-resident block ----
    int r4 = (lane >> 4) * 4;
#pragma unroll
    for (int mi = 0; mi < 8; ++mi)
#pragma unroll
        for (int ni = 0; ni < 4; ++ni) {
            int col = n0 + wn * 64 + (ni >> 1) * 32 + (ni & 1) * 16 + fr;
            if (col >= nmax) continue;
            int row = m0 + wm * 128 + (mi >> 2) * 64 + (mi & 3) * 16 + r4;
#pragma unroll
            for (int rr = 0; rr < 4; ++rr)
                C[(size_t)(row + rr) * ldc + col] = acc[mi][ni][rr];
        }
}

// ---------------- host ----------------
extern "C" void kernel_launch(void* const* d_in, const int* in_sizes, int n_in,
                              void* d_out, int out_size, void* d_ws, size_t ws_size,
                              hipStream_t stream) {
    (void)in_sizes; (void)n_in; (void)out_size;
    const int*   tok   = (const int*)d_in[0];
    const float* emb   = (const float*)d_in[1];
    const float* normw = (const float*)d_in[2];
    const float* inw   = (const float*)d_in[3];
    const float* cw    = (const float*)d_in[4];
    const float* cb    = (const float*)d_in[5];
    const float* xpw   = (const float*)d_in[6];
    const float* dtw   = (const float*)d_in[7];
    const float* dtb   = (const float*)d_in[8];
    const float* alog  = (const float*)d_in[9];
    const float* Dp    = (const float*)d_in[10];
    const float* outw  = (const float*)d_in[11];
    const float* normf = (const float*)d_in[12];
    const float* lmw   = (const float*)d_in[13];
    float* out = (float*)d_out;

    char* p = (char*)d_ws;
    auto alloc = [&](size_t bytes) { char* r = p; p += (bytes + 255) & ~(size_t)255; return r; };
    float* x     = (float*)alloc((size_t)MROWS * DM * 4);
    u16*   xnb   = (u16*)  alloc((size_t)MROWS * DM * 2);
    float* xz    = (float*)alloc((size_t)MROWS * 2 * DI * 4);
    float* uc    = (float*)alloc((size_t)MROWS * DI * 4);
    u16*   ucb   = (u16*)  alloc((size_t)MROWS * DI * 2);
    float* xdbl  = (float*)alloc((size_t)MROWS * 128 * 4);
    u16*   xdblb = (u16*)  alloc((size_t)MROWS * 64 * 2);
    float* delta = (float*)alloc((size_t)MROWS * DI * 4);
    u16*   ybf   = (u16*)  alloc((size_t)MROWS * DI * 2);
    u16*   winb  = (u16*)  alloc((size_t)NB * (2 * DI) * DM * 2);
    u16*   wxpb  = (u16*)  alloc((size_t)NB * 128 * DI * 2);
    u16*   wdtb  = (u16*)  alloc((size_t)NB * DI * 64 * 2);
    u16*   woutb = (u16*)  alloc((size_t)NB * DM * DI * 2);
    u16*   wlmb  = (u16*)  alloc((size_t)VOCP * DM * 2);
    if ((size_t)(p - (char*)d_ws) > ws_size) return;  // insufficient scratch: fail loudly

    // ---- one fused weight-conversion launch (9 segments) ----
    CvtArgs ca;
    int blk = 0;
    auto seg = [&](int idx, const float* s, u16* d, int sr, int sc, int sld, int dc, int dr) {
        int t4 = dr * dc / 4;
        ca.seg[idx] = CvtSeg{s, d, sr, sc, sld, dc, blk, t4};
        blk += (t4 + 255) / 256;
    };
    seg(0, lmw, wlmb, VOC, DM, DM, DM, VOCP);
    seg(1, inw,                          winb,                          2 * DI, DM, DM, DM, 2 * DI);
    seg(2, inw + (size_t)2 * DI * DM,    winb + (size_t)2 * DI * DM,    2 * DI, DM, DM, DM, 2 * DI);
    seg(3, xpw,                          wxpb,                          80, DI, DI, DI, 128);
    seg(4, xpw + (size_t)80 * DI,        wxpb + (size_t)128 * DI,       80, DI, DI, DI, 128);
    seg(5, dtw,                          wdtb,                          DI, 48, 48, 64, DI);
    seg(6, dtw + (size_t)DI * 48,        wdtb + (size_t)DI * 64,        DI, 48, 48, 64, DI);
    seg(7, outw,                         woutb,                         DM, DI, DI, DI, DM);
    seg(8, outw + (size_t)DM * DI,       woutb + (size_t)DM * DI,       DM, DI, DI, DI, DM);
    k_cvt_multi<<<dim3(blk), 256, 0, stream>>>(ca);

    // embedding + layer-0 rmsnorm fused
    k_embed_rms<<<MROWS, 256, 0, stream>>>(tok, emb, normw, x, xnb);

    for (int i = 0; i < NB; ++i) {
        if (i > 0)
            k_rmsnorm_bf16<<<MROWS, 256, 0, stream>>>(x, normw + i * DM, xnb);

        k_gemm_bt<0><<<dim3(16 * (2 * DI / 128)), 256, 0, stream>>>(
            xnb, winb + (size_t)i * 2 * DI * DM, xz, nullptr, nullptr, DM, 2 * DI, 16);

        k_conv_silu<<<dim3(DI / 256, MROWS), 256, 0, stream>>>(
            xz, cw + (size_t)i * DI * 4, cb + (size_t)i * DI, uc, ucb);

        // x_proj (N=128)
        k_gemm_bt<0><<<dim3(16 * 1), 256, 0, stream>>>(
            ucb, wxpb + (size_t)i * 128 * DI, xdbl, nullptr, nullptr, DI, 128, 16);

        // dt input -> bf16 (cols 0..63 of xdbl)
        { long t4 = (long)MROWS * 64 / 4;
          k_cvt_pad4<<<dim3((unsigned)((t4 + 255) / 256)), 256, 0, stream>>>(
              xdbl, xdblb, MROWS, 64, 128, 64, t4); }

        // dt GEMM (K=64) with fused softplus(v + dt_bias) -> delta
        k_gemm_bt<2><<<dim3(16 * (DI / 128)), 256, 0, stream>>>(
            xdblb, wdtb + (size_t)i * DI * 64, delta, nullptr, dtb + (size_t)i * DI,
            64, DI, 16);

        k_scan2<<<dim3(NB * (DI / 16)), 512, 0, stream>>>(
            delta, uc, xdbl, xz, alog + (size_t)i * DI * DSN, Dp + i * DI, ybf);

        // out_proj (N=768) with fused residual add
        k_gemm_bt<1><<<dim3(16 * (DM / 128)), 256, 0, stream>>>(
            ybf, woutb + (size_t)i * DM * DI, x, x, nullptr, DI, DM, 16);
    }

    k_rmsnorm_bf16<<<MROWS, 256, 0, stream>>>(x, normf, xnb);
    k_gemm256<DM><<<dim3(8 * (VOCP / 256)), 512, 0, stream>>>(
        xnb, wlmb, out, VOC, VOC, 8);
}

// Round 12
// 794.326 us; speedup vs baseline: 3.1306x; 3.1306x over previous
//
#include <hip/hip_runtime.h>
#include <hip/hip_bf16.h>
#include <math.h>

#define DM 768
#define DI 1536
#define DSN 16
#define NB 2
#define SL 1024
#define MROWS 2048
#define VOC 50257
#define VOCP 50432           // padded to multiple of 256 for the 256^2 lm_head GEMM
#define EPSR 1e-5f

typedef __attribute__((ext_vector_type(8))) short short8;
typedef __attribute__((ext_vector_type(4))) float f32x4;
typedef __attribute__((ext_vector_type(4))) unsigned short us4;
typedef unsigned short u16;

__device__ inline u16 f2bf(float f) {
    unsigned u = __builtin_bit_cast(unsigned, f);
    u += 0x7FFFu + ((u >> 16) & 1u);   // round-to-nearest-even
    return (u16)(u >> 16);
}

#define G_LDS16(g, l) __builtin_amdgcn_global_load_lds( \
    (const __attribute__((address_space(1))) void*)(g), \
    (__attribute__((address_space(3))) void*)(l), 16, 0, 0)

// ---------------- embedding gather + layer-0 RMSNorm (fused) ----------------
__global__ __launch_bounds__(256)
void k_embed_rms(const int* __restrict__ tok, const float* __restrict__ emb,
                 const float* __restrict__ w, float* __restrict__ x,
                 u16* __restrict__ out) {
    int r = blockIdx.x;
    int t = tok[r];
    const float* src = emb + (size_t)t * DM;
    int c0 = threadIdx.x * 3;
    float v[3]; float ss = 0.f;
#pragma unroll
    for (int i = 0; i < 3; ++i) {
        v[i] = src[c0 + i]; ss += v[i] * v[i];
        x[(size_t)r * DM + c0 + i] = v[i];
    }
#pragma unroll
    for (int o = 32; o > 0; o >>= 1) ss += __shfl_down(ss, o);
    __shared__ float s[4];
    int lane = threadIdx.x & 63, wv = threadIdx.x >> 6;
    if (lane == 0) s[wv] = ss;
    __syncthreads();
    float sc = rsqrtf((s[0] + s[1] + s[2] + s[3]) / (float)DM + EPSR);
#pragma unroll
    for (int i = 0; i < 3; ++i)
        out[(size_t)r * DM + c0 + i] = f2bf(v[i] * sc * w[c0 + i]);
}

// ---------------- RMSNorm -> bf16 ----------------
__global__ __launch_bounds__(256)
void k_rmsnorm_bf16(const float* __restrict__ x, const float* __restrict__ w,
                    u16* __restrict__ out) {
    int r = blockIdx.x;
    const float* row = x + (size_t)r * DM;
    int c0 = threadIdx.x * 3;
    float v[3]; float ss = 0.f;
#pragma unroll
    for (int i = 0; i < 3; ++i) { v[i] = row[c0 + i]; ss += v[i] * v[i]; }
#pragma unroll
    for (int o = 32; o > 0; o >>= 1) ss += __shfl_down(ss, o);
    __shared__ float s[4];
    int lane = threadIdx.x & 63, wv = threadIdx.x >> 6;
    if (lane == 0) s[wv] = ss;
    __syncthreads();
    float sc = rsqrtf((s[0] + s[1] + s[2] + s[3]) / (float)DM + EPSR);
#pragma unroll
    for (int i = 0; i < 3; ++i)
        out[(size_t)r * DM + c0 + i] = f2bf(v[i] * sc * w[c0 + i]);
}

// -------- fused multi-segment f32 -> bf16 weight conversion (one launch) --------
struct CvtSeg { const float* src; u16* dst; int sr, sc, sld, dc, blk0, total4; };
struct CvtArgs { CvtSeg seg[9]; };

__global__ __launch_bounds__(256)
void k_cvt_multi(CvtArgs a) {
    int b = blockIdx.x;
    int s = 0;
#pragma unroll
    for (int q = 1; q < 9; ++q) if (a.seg[q].blk0 <= b) s = q;
    const CvtSeg& g = a.seg[s];
    long i4 = (long)(b - g.blk0) * 256 + threadIdx.x;
    if (i4 >= g.total4) return;
    long i = i4 * 4;
    int r = (int)(i / g.dc), c0 = (int)(i % g.dc);
    us4 o;
#pragma unroll
    for (int e = 0; e < 4; ++e) {
        int c = c0 + e;
        float v = (r < g.sr && c < g.sc) ? g.src[(size_t)r * g.sld + c] : 0.f;
        o[e] = f2bf(v);
    }
    *(us4*)&g.dst[i] = o;
}

// ---------------- f32 -> bf16 with 2D pad, 4 elems/thread (dc % 4 == 0) ----------------
__global__ void k_cvt_pad4(const float* __restrict__ src, u16* __restrict__ dst,
                           int sr, int sc, int sld, int dc, long total4) {
    long i4 = (long)blockIdx.x * 256 + threadIdx.x;
    if (i4 >= total4) return;
    long i = i4 * 4;
    int r = (int)(i / dc), c0 = (int)(i % dc);
    us4 o;
#pragma unroll
    for (int e = 0; e < 4; ++e) {
        int c = c0 + e;
        float v = (r < sr && c < sc) ? src[(size_t)r * sld + c] : 0.f;
        o[e] = f2bf(v);
    }
    *(us4*)&dst[i] = o;
}

// ---------------- causal depthwise conv (width 4) + bias + silu ----------------
__global__ void k_conv_silu(const float* __restrict__ xz, const float* __restrict__ cw,
                            const float* __restrict__ cb, float* __restrict__ uc,
                            u16* __restrict__ ucb) {
    int d = blockIdx.x * 256 + threadIdx.x;   // 0..1535
    int r = blockIdx.y;                       // 0..2047
    int l = r & (SL - 1);
    float acc = cb[d];
#pragma unroll
    for (int j = 0; j < 4; ++j) {
        int ls = l - 3 + j;
        if (ls >= 0) acc += xz[(size_t)(r - 3 + j) * (2 * DI) + d] * cw[d * 4 + j];
    }
    float s = acc / (1.f + __expf(-acc));
    uc[(size_t)r * DI + d] = s;
    ucb[(size_t)r * DI + d] = f2bf(s);
}

// ---------------- chunked selective scan (8 chunks x 128 steps, 1 kernel) --------------
__global__ __launch_bounds__(512)
void k_scan2(const float* __restrict__ delta, const float* __restrict__ uc,
             const float* __restrict__ xdbl, const float* __restrict__ xz,
             const float* __restrict__ alog, const float* __restrict__ Dp,
             u16* __restrict__ ybf) {
    __shared__ float ds2[8][16][20], us2[8][16][20], bn2[8][16][20], cn2[8][16][20];
    __shared__ float Sm[8][16][16], Pm[8][16][16];
    int b  = blockIdx.x / 96;
    int d0 = (blockIdx.x % 96) * 16;
    int tid = threadIdx.x, w = tid >> 6, lane = tid & 63;
    int ch = lane >> 2, nq = lane & 3;
    int d = d0 + ch;
    float A[4];
#pragma unroll
    for (int k = 0; k < 4; ++k) A[k] = -__expf(alog[d * DSN + nq + 4 * k]);
    int tb = w * 128;

    // ---- phase 1 ----
    float h[4] = {0.f, 0.f, 0.f, 0.f};
    float sdl = 0.f;
    for (int t0 = 0; t0 < 128; t0 += 16) {
        int row0 = b * SL + tb + t0;
#pragma unroll
        for (int i = 0; i < 4; ++i) {
            int lin = i * 64 + lane, tt = lin >> 4, cc = lin & 15;
            size_t row = (size_t)(row0 + tt);
            ds2[w][cc][tt] = delta[row * DI + d0 + cc];
            us2[w][cc][tt] = uc[row * DI + d0 + cc];
            bn2[w][cc][tt] = xdbl[row * 128 + 48 + cc];
        }
#pragma unroll
        for (int g4 = 0; g4 < 4; ++g4) {
            f32x4 dl = *(const f32x4*)&ds2[w][ch][g4 * 4];
            f32x4 uv = *(const f32x4*)&us2[w][ch][g4 * 4];
            f32x4 bv[4];
#pragma unroll
            for (int k = 0; k < 4; ++k) bv[k] = *(const f32x4*)&bn2[w][nq + 4 * k][g4 * 4];
#pragma unroll
            for (int s = 0; s < 4; ++s) {
                float du = dl[s] * uv[s];
                sdl += dl[s];
#pragma unroll
                for (int k = 0; k < 4; ++k) {
                    float dA = __expf(dl[s] * A[k]);
                    h[k] = h[k] * dA + du * bv[k][s];
                }
            }
        }
    }
#pragma unroll
    for (int k = 0; k < 4; ++k) {
        Sm[w][ch][nq + 4 * k] = h[k];
        Pm[w][ch][nq + 4 * k] = __expf(A[k] * sdl);
    }
    __syncthreads();
    if (tid < 256) {
        int c2 = tid >> 4, n2 = tid & 15;
        float H = 0.f;
#pragma unroll
        for (int g = 0; g < 8; ++g) {
            float hi = H;
            H = Pm[g][c2][n2] * H + Sm[g][c2][n2];
            Sm[g][c2][n2] = hi;
        }
    }
    __syncthreads();
    // ---- phase 3 ----
    float Dv = Dp[d];
#pragma unroll
    for (int k = 0; k < 4; ++k) h[k] = Sm[w][ch][nq + 4 * k];
    for (int t0 = 0; t0 < 128; t0 += 16) {
        int row0 = b * SL + tb + t0;
#pragma unroll
        for (int i = 0; i < 4; ++i) {
            int lin = i * 64 + lane, tt = lin >> 4, cc = lin & 15;
            size_t row = (size_t)(row0 + tt);
            ds2[w][cc][tt] = delta[row * DI + d0 + cc];
            us2[w][cc][tt] = uc[row * DI + d0 + cc];
            bn2[w][cc][tt] = xdbl[row * 128 + 48 + cc];
            cn2[w][cc][tt] = xdbl[row * 128 + 64 + cc];
        }
#pragma unroll
        for (int g4 = 0; g4 < 4; ++g4) {
            f32x4 dl = *(const f32x4*)&ds2[w][ch][g4 * 4];
            f32x4 uv = *(const f32x4*)&us2[w][ch][g4 * 4];
            f32x4 bv[4], cv[4];
#pragma unroll
            for (int k = 0; k < 4; ++k) {
                bv[k] = *(const f32x4*)&bn2[w][nq + 4 * k][g4 * 4];
                cv[k] = *(const f32x4*)&cn2[w][nq + 4 * k][g4 * 4];
            }
#pragma unroll
            for (int s = 0; s < 4; ++s) {
                float du = dl[s] * uv[s];
                float p = 0.f;
#pragma unroll
                for (int k = 0; k < 4; ++k) {
                    float dA = __expf(dl[s] * A[k]);
                    h[k] = h[k] * dA + du * bv[k][s];
                    p += h[k] * cv[k][s];
                }
                p += __shfl_xor(p, 1);
                p += __shfl_xor(p, 2);
                if (nq == 0) {
                    size_t row = (size_t)(row0 + g4 * 4 + s);
                    float z = xz[row * (2 * DI) + DI + d];
                    float y = p + uv[s] * Dv;
                    y *= z / (1.f + __expf(-z));
                    ybf[row * DI + d] = f2bf(y);
                }
            }
        }
    }
}

// ------- 128^2 bf16 MFMA GEMM (layer GEMMs), fused epilogue --------
// EPIL: 0 = plain, 1 = add residual, 2 = softplus(v + bias[col])
template <int EPIL>
__global__ __launch_bounds__(256)
void k_gemm_bt(const u16* __restrict__ A, const u16* __restrict__ W,
               float* C, const float* RES,
               const float* __restrict__ BIASV,
               int K, int ldc, int nTm) {
    __shared__ u16 Al[128 * 32];
    __shared__ u16 Wl[128 * 32];
    int nwg = gridDim.x;
    int qc = nwg >> 3, rc = nwg & 7;
    int xcd = blockIdx.x & 7, j = blockIdx.x >> 3;
    int wg = (xcd < rc ? xcd * (qc + 1) : rc * (qc + 1) + (xcd - rc) * qc) + j;
    int m0 = (wg % nTm) * 128, n0 = (wg / nTm) * 128;

    int tid = threadIdx.x, wave = tid >> 6, lane = tid & 63;
    int wm = wave >> 1, wn = wave & 1;
    f32x4 acc[4][4] = {};
    const int rS = (lane >> 2);
    const int kS = (((lane & 3) ^ ((lane >> 3) & 3)) * 8);
    const int kofs = (((lane >> 4) ^ ((lane >> 1) & 3)) * 8);
    const int fr = lane & 15;

    for (int k0 = 0; k0 < K; k0 += 32) {
#pragma unroll
        for (int i = 0; i < 2; ++i) {
            int rowA = m0 + wave * 32 + i * 16 + rS;
            G_LDS16(A + (size_t)rowA * K + k0 + kS, &Al[wave * 1024 + i * 512]);
            int rowW = n0 + wave * 32 + i * 16 + rS;
            G_LDS16(W + (size_t)rowW * K + k0 + kS, &Wl[wave * 1024 + i * 512]);
        }
        __syncthreads();
        short8 af[4], bfr[4];
#pragma unroll
        for (int f = 0; f < 4; ++f) {
            af[f]  = *(const short8*)&Al[(wm * 64 + f * 16 + fr) * 32 + kofs];
            bfr[f] = *(const short8*)&Wl[(wn * 64 + f * 16 + fr) * 32 + kofs];
        }
#pragma unroll
        for (int i = 0; i < 4; ++i)
#pragma unroll
            for (int jj = 0; jj < 4; ++jj)
                acc[i][jj] = __builtin_amdgcn_mfma_f32_16x16x32_bf16(af[i], bfr[jj], acc[i][jj], 0, 0, 0);
        __syncthreads();
    }
    int r4 = (lane >> 4) * 4;
#pragma unroll
    for (int i = 0; i < 4; ++i)
#pragma unroll
        for (int jj = 0; jj < 4; ++jj) {
            int col = n0 + wn * 64 + jj * 16 + fr;
            float bia = (EPIL == 2) ? BIASV[col] : 0.f;
#pragma unroll
            for (int rr = 0; rr < 4; ++rr) {
                int row = m0 + wm * 64 + i * 16 + r4 + rr;
                size_t off = (size_t)row * ldc + col;
                float v = acc[i][jj][rr];
                if (EPIL == 1) v += RES[off];
                if (EPIL == 2) { v += bia; v = (v > 20.f) ? v : log1pf(__expf(v)); }
                C[off] = v;
            }
        }
}

// ===== 256^2 8-phase bf16 GEMM (lm_head), BK=32 / 64 KiB LDS / 2 blocks-per-CU =====
// 512 thr = 8 waves (2M x 4N); per-wave 128x64 C; counted vmcnt(3) (1 load/half-tile);
// LDS [buf][A/B][half][128x32] with the PROVEN 128^2 swizzle pair (0-conflict layout).
// NOTE: launch_bounds MUST stay (512,2) — (512,4) caps VGPR at 64 and spills acc (r11).
#define BAR  __builtin_amdgcn_s_barrier()
#define LGK0 do { asm volatile("s_waitcnt lgkmcnt(0)" ::: "memory"); \
                  __builtin_amdgcn_sched_barrier(0); } while (0)
#define VMC3 asm volatile("s_waitcnt vmcnt(3)" ::: "memory")
#define VMC0 asm volatile("s_waitcnt vmcnt(0)" ::: "memory")

// stage half-tile (t, op, half): 8 KB; each wave ONE global_load_lds of 1 KB (16 rows x 32)
#define STAGE1(t, op, half, GB, RB) do {                                      \
    const u16* _g = (GB) + (size_t)((RB) + (half) * 128 + (w << 4) + srow) * K \
                    + (t) * 32 + scol;                                         \
    G_LDS16(_g, &lds[(t) & 1][op][half][w << 9]);                              \
} while (0)

#define RDA(dst, t, mq) do {                                                   \
    _Pragma("unroll") for (int _m = 0; _m < 4; ++_m)                           \
        dst[_m] = *(const short8*)&lds[(t) & 1][0][wm]                         \
            [((mq) * 64 + _m * 16 + fr) * 32 + rd_sw];                         \
} while (0)

#define RDB(t, nq) do {                                                       \
    _Pragma("unroll") for (int _n = 0; _n < 2; ++_n)                           \
        bfv[_n] = *(const short8*)&lds[(t) & 1][1][wbh]                        \
            [(wbr * 64 + (nq) * 32 + _n * 16 + fr) * 32 + rd_sw];              \
} while (0)

#define MM8(AF, mq, nq) do {                                                  \
    __builtin_amdgcn_s_setprio(1);                                            \
    _Pragma("unroll") for (int _m = 0; _m < 4; ++_m)                           \
    _Pragma("unroll") for (int _n = 0; _n < 2; ++_n)                           \
        acc[(mq) * 4 + _m][(nq) * 2 + _n] =                                    \
            __builtin_amdgcn_mfma_f32_16x16x32_bf16(                           \
                AF[_m], bfv[_n], acc[(mq) * 4 + _m][(nq) * 2 + _n], 0, 0, 0);  \
    __builtin_amdgcn_s_setprio(0);                                            \
} while (0)

template <int K>
__global__ __launch_bounds__(512, 2)
void k_gemm256(const u16* __restrict__ Ap, const u16* __restrict__ Wp,
               float* __restrict__ C, int ldc, int nmax, int nTm) {
    constexpr int NT = K / 32;       // 24 K-tiles (even, >= 4)
    constexpr int NI = NT / 2;       // 12 pair iterations
    __shared__ __align__(16) u16 lds[2][2][2][4096];  // 64 KiB: [buf][A/B][half][128x32]

    int per8 = gridDim.x >> 3;
    int wg = (blockIdx.x & 7) * per8 + (blockIdx.x >> 3);
    int m0 = (wg % nTm) * 256, n0 = (wg / nTm) * 256;

    int tid = threadIdx.x, w = tid >> 6, lane = tid & 63;
    int wm = w >> 2, wn = w & 3, wbh = wn >> 1, wbr = wn & 1;
    int fr = lane & 15;
    // proven 128^2 swizzle pair for [row][32] layout (64B row stride):
    int rd_sw = (((lane >> 4) ^ ((lane >> 1) & 3)) * 8);   // read col offset (elems)
    int srow  = lane >> 2;                                 // staging row 0..15
    int scol  = (((lane & 3) ^ ((lane >> 3) & 3)) * 8);    // pre-swizzled source col

    f32x4 acc[8][4] = {};
    short8 af0[4], af1[4], bfv[2];

    // ---- prologue: tile0 full + tile1 {A0,A1,B0}; 7 loads/wave; vmcnt(3) => tile0 ----
    STAGE1(0, 0, 0, Ap, m0); STAGE1(0, 0, 1, Ap, m0);
    STAGE1(0, 1, 0, Wp, n0); STAGE1(0, 1, 1, Wp, n0);
    STAGE1(1, 0, 0, Ap, m0); STAGE1(1, 0, 1, Ap, m0);
    STAGE1(1, 1, 0, Wp, n0);
    VMC3; BAR;

    // ---- main loop: vmcnt(3) at phases 4 & 8 (3 half-tiles in flight) ----
    for (int i = 0; i < NI - 1; ++i) {
        const int ta = 2 * i, tb = 2 * i + 1;
        // P1
        RDA(af0, ta, 0); RDB(ta, 0);
        STAGE1(tb, 1, 1, Wp, n0);
        BAR; LGK0; MM8(af0, 0, 0); BAR;
        // P2
        RDA(af1, ta, 1);
        STAGE1(ta + 2, 0, 0, Ap, m0);
        BAR; LGK0; MM8(af1, 1, 0); BAR;
        // P3
        RDB(ta, 1);
        STAGE1(ta + 2, 0, 1, Ap, m0);
        BAR; LGK0; MM8(af1, 1, 1); BAR;
        // P4
        STAGE1(ta + 2, 1, 0, Wp, n0);
        BAR; MM8(af0, 0, 1); VMC3; BAR;
        // P5
        RDA(af0, tb, 0); RDB(tb, 0);
        STAGE1(ta + 2, 1, 1, Wp, n0);
        BAR; LGK0; MM8(af0, 0, 0); BAR;
        // P6
        RDA(af1, tb, 1);
        STAGE1(ta + 3, 0, 0, Ap, m0);
        BAR; LGK0; MM8(af1, 1, 0); BAR;
        // P7
        RDB(tb, 1);
        STAGE1(ta + 3, 0, 1, Ap, m0);
        BAR; LGK0; MM8(af1, 1, 1); BAR;
        // P8
        STAGE1(ta + 3, 1, 0, Wp, n0);
        BAR; MM8(af0, 0, 1); VMC3; BAR;
    }
    // ---- peeled last pair: only P1 stages; vmcnt(0) at P4 ----
    {
        const int ta = NT - 2, tb = NT - 1;
        RDA(af0, ta, 0); RDB(ta, 0);
        STAGE1(tb, 1, 1, Wp, n0);
        BAR; LGK0; MM8(af0, 0, 0); BAR;
        RDA(af1, ta, 1);
        BAR; LGK0; MM8(af1, 1, 0); BAR;
        RDB(ta, 1);
        BAR; LGK0; MM8(af1, 1, 1); BAR;
        BAR; MM8(af0, 0, 1); VMC0; BAR;
        RDA(af0, tb, 0); RDB(tb, 0);
        BAR; LGK0; MM8(af0, 0, 0); BAR;
        RDA(af1, tb, 1);
        BAR; LGK0; MM8(af1, 1, 0); BAR;
        RDB(tb, 1);
        BAR; LGK0; MM8(af1, 1, 1); BAR;
        BAR; MM8(af0, 0, 1); BAR;
    }

    // ---- epilogue: C write (registers only); overlaps the co-resident block ----
    int r4 = (lane >> 4) * 4;
#pragma unroll
    for (int mi = 0; mi < 8; ++mi)
#pragma unroll
        for (int ni = 0; ni < 4; ++ni) {
            int col = n0 + wn * 64 + (ni >> 1) * 32 + (ni & 1) * 16 + fr;
            if (col >= nmax) continue;
            int row = m0 + wm * 128 + (mi >> 2) * 64 + (mi & 3) * 16 + r4;
#pragma unroll
            for (int rr = 0; rr < 4; ++rr)
                C[(size_t)(row + rr) * ldc + col] = acc[mi][ni][rr];
        }
}

// ---------------- host ----------------
extern "C" void kernel_launch(void* const* d_in, const int* in_sizes, int n_in,
                              void* d_out, int out_size, void* d_ws, size_t ws_size,
                              hipStream_t stream) {
    (void)in_sizes; (void)n_in; (void)out_size;
    const int*   tok   = (const int*)d_in[0];
    const float* emb   = (const float*)d_in[1];
    const float* normw = (const float*)d_in[2];
    const float* inw   = (const float*)d_in[3];
    const float* cw    = (const float*)d_in[4];
    const float* cb    = (const float*)d_in[5];
    const float* xpw   = (const float*)d_in[6];
    const float* dtw   = (const float*)d_in[7];
    const float* dtb   = (const float*)d_in[8];
    const float* alog  = (const float*)d_in[9];
    const float* Dp    = (const float*)d_in[10];
    const float* outw  = (const float*)d_in[11];
    const float* normf = (const float*)d_in[12];
    const float* lmw   = (const float*)d_in[13];
    float* out = (float*)d_out;

    char* p = (char*)d_ws;
    auto alloc = [&](size_t bytes) { char* r = p; p += (bytes + 255) & ~(size_t)255; return r; };
    float* x     = (float*)alloc((size_t)MROWS * DM * 4);
    u16*   xnb   = (u16*)  alloc((size_t)MROWS * DM * 2);
    float* xz    = (float*)alloc((size_t)MROWS * 2 * DI * 4);
    float* uc    = (float*)alloc((size_t)MROWS * DI * 4);
    u16*   ucb   = (u16*)  alloc((size_t)MROWS * DI * 2);
    float* xdbl  = (float*)alloc((size_t)MROWS * 128 * 4);
    u16*   xdblb = (u16*)  alloc((size_t)MROWS * 64 * 2);
    float* delta = (float*)alloc((size_t)MROWS * DI * 4);
    u16*   ybf   = (u16*)  alloc((size_t)MROWS * DI * 2);
    u16*   winb  = (u16*)  alloc((size_t)NB * (2 * DI) * DM * 2);
    u16*   wxpb  = (u16*)  alloc((size_t)NB * 128 * DI * 2);
    u16*   wdtb  = (u16*)  alloc((size_t)NB * DI * 64 * 2);
    u16*   woutb = (u16*)  alloc((size_t)NB * DM * DI * 2);
    u16*   wlmb  = (u16*)  alloc((size_t)VOCP * DM * 2);
    if ((size_t)(p - (char*)d_ws) > ws_size) return;  // insufficient scratch: fail loudly

    // ---- one fused weight-conversion launch (9 segments) ----
    CvtArgs ca;
    int blk = 0;
    auto seg = [&](int idx, const float* s, u16* d, int sr, int sc, int sld, int dc, int dr) {
        int t4 = dr * dc / 4;
        ca.seg[idx] = CvtSeg{s, d, sr, sc, sld, dc, blk, t4};
        blk += (t4 + 255) / 256;
    };
    seg(0, lmw, wlmb, VOC, DM, DM, DM, VOCP);
    seg(1, inw,                          winb,                          2 * DI, DM, DM, DM, 2 * DI);
    seg(2, inw + (size_t)2 * DI * DM,    winb + (size_t)2 * DI * DM,    2 * DI, DM, DM, DM, 2 * DI);
    seg(3, xpw,                          wxpb,                          80, DI, DI, DI, 128);
    seg(4, xpw + (size_t)80 * DI,        wxpb + (size_t)128 * DI,       80, DI, DI, DI, 128);
    seg(5, dtw,                          wdtb,                          DI, 48, 48, 64, DI);
    seg(6, dtw + (size_t)DI * 48,        wdtb + (size_t)DI * 64,        DI, 48, 48, 64, DI);
    seg(7, outw,                         woutb,                         DM, DI, DI, DI, DM);
    seg(8, outw + (size_t)DM * DI,       woutb + (size_t)DM * DI,       DM, DI, DI, DI, DM);
    k_cvt_multi<<<dim3(blk), 256, 0, stream>>>(ca);

    // embedding + layer-0 rmsnorm fused
    k_embed_rms<<<MROWS, 256, 0, stream>>>(tok, emb, normw, x, xnb);

    for (int i = 0; i < NB; ++i) {
        if (i > 0)
            k_rmsnorm_bf16<<<MROWS, 256, 0, stream>>>(x, normw + i * DM, xnb);

        k_gemm_bt<0><<<dim3(16 * (2 * DI / 128)), 256, 0, stream>>>(
            xnb, winb + (size_t)i * 2 * DI * DM, xz, nullptr, nullptr, DM, 2 * DI, 16);

        k_conv_silu<<<dim3(DI / 256, MROWS), 256, 0, stream>>>(
            xz, cw + (size_t)i * DI * 4, cb + (size_t)i * DI, uc, ucb);

        // x_proj (N=128)
        k_gemm_bt<0><<<dim3(16 * 1), 256, 0, stream>>>(
            ucb, wxpb + (size_t)i * 128 * DI, xdbl, nullptr, nullptr, DI, 128, 16);

        // dt input -> bf16 (cols 0..63 of xdbl)
        { long t4 = (long)MROWS * 64 / 4;
          k_cvt_pad4<<<dim3((unsigned)((t4 + 255) / 256)), 256, 0, stream>>>(
              xdbl, xdblb, MROWS, 64, 128, 64, t4); }

        // dt GEMM (K=64) with fused softplus(v + dt_bias) -> delta
        k_gemm_bt<2><<<dim3(16 * (DI / 128)), 256, 0, stream>>>(
            xdblb, wdtb + (size_t)i * DI * 64, delta, nullptr, dtb + (size_t)i * DI,
            64, DI, 16);

        k_scan2<<<dim3(NB * (DI / 16)), 512, 0, stream>>>(
            delta, uc, xdbl, xz, alog + (size_t)i * DI * DSN, Dp + i * DI, ybf);

        // out_proj (N=768) with fused residual add
        k_gemm_bt<1><<<dim3(16 * (DM / 128)), 256, 0, stream>>>(
            ybf, woutb + (size_t)i * DM * DI, x, x, nullptr, DI, DM, 16);
    }

    k_rmsnorm_bf16<<<MROWS, 256, 0, stream>>>(x, normf, xnb);
    k_gemm256<DM><<<dim3(8 * (VOCP / 256)), 512, 0, stream>>>(
        xnb, wlmb, out, VOC, VOC, 8);
}

// Round 13
// 747.709 us; speedup vs baseline: 3.3257x; 1.0623x over previous
//
#include <hip/hip_runtime.h>
#include <hip/hip_bf16.h>
#include <math.h>

#define DM 768
#define DI 1536
#define DSN 16
#define NB 2
#define SL 1024
#define MROWS 2048
#define VOC 50257
#define VOCP 50432           // padded to multiple of 256 for the 256^2 lm_head GEMM
#define EPSR 1e-5f

typedef __attribute__((ext_vector_type(8))) short short8;
typedef __attribute__((ext_vector_type(4))) float f32x4;
typedef __attribute__((ext_vector_type(4))) unsigned short us4;
typedef unsigned short u16;

__device__ inline u16 f2bf(float f) {
    unsigned u = __builtin_bit_cast(unsigned, f);
    u += 0x7FFFu + ((u >> 16) & 1u);   // round-to-nearest-even
    return (u16)(u >> 16);
}

#define G_LDS16(g, l) __builtin_amdgcn_global_load_lds( \
    (const __attribute__((address_space(1))) void*)(g), \
    (__attribute__((address_space(3))) void*)(l), 16, 0, 0)

// ---------------- embedding gather + layer-0 RMSNorm (fused) ----------------
__global__ __launch_bounds__(256)
void k_embed_rms(const int* __restrict__ tok, const float* __restrict__ emb,
                 const float* __restrict__ w, float* __restrict__ x,
                 u16* __restrict__ out) {
    int r = blockIdx.x;
    int t = tok[r];
    const float* src = emb + (size_t)t * DM;
    int c0 = threadIdx.x * 3;
    float v[3]; float ss = 0.f;
#pragma unroll
    for (int i = 0; i < 3; ++i) {
        v[i] = src[c0 + i]; ss += v[i] * v[i];
        x[(size_t)r * DM + c0 + i] = v[i];
    }
#pragma unroll
    for (int o = 32; o > 0; o >>= 1) ss += __shfl_down(ss, o);
    __shared__ float s[4];
    int lane = threadIdx.x & 63, wv = threadIdx.x >> 6;
    if (lane == 0) s[wv] = ss;
    __syncthreads();
    float sc = rsqrtf((s[0] + s[1] + s[2] + s[3]) / (float)DM + EPSR);
#pragma unroll
    for (int i = 0; i < 3; ++i)
        out[(size_t)r * DM + c0 + i] = f2bf(v[i] * sc * w[c0 + i]);
}

// ---------------- RMSNorm -> bf16 ----------------
__global__ __launch_bounds__(256)
void k_rmsnorm_bf16(const float* __restrict__ x, const float* __restrict__ w,
                    u16* __restrict__ out) {
    int r = blockIdx.x;
    const float* row = x + (size_t)r * DM;
    int c0 = threadIdx.x * 3;
    float v[3]; float ss = 0.f;
#pragma unroll
    for (int i = 0; i < 3; ++i) { v[i] = row[c0 + i]; ss += v[i] * v[i]; }
#pragma unroll
    for (int o = 32; o > 0; o >>= 1) ss += __shfl_down(ss, o);
    __shared__ float s[4];
    int lane = threadIdx.x & 63, wv = threadIdx.x >> 6;
    if (lane == 0) s[wv] = ss;
    __syncthreads();
    float sc = rsqrtf((s[0] + s[1] + s[2] + s[3]) / (float)DM + EPSR);
#pragma unroll
    for (int i = 0; i < 3; ++i)
        out[(size_t)r * DM + c0 + i] = f2bf(v[i] * sc * w[c0 + i]);
}

// -------- fused multi-segment f32 -> bf16 weight conversion (one launch) --------
struct CvtSeg { const float* src; u16* dst; int sr, sc, sld, dc, blk0, total4; };
struct CvtArgs { CvtSeg seg[9]; };

__global__ __launch_bounds__(256)
void k_cvt_multi(CvtArgs a) {
    int b = blockIdx.x;
    int s = 0;
#pragma unroll
    for (int q = 1; q < 9; ++q) if (a.seg[q].blk0 <= b) s = q;
    const CvtSeg& g = a.seg[s];
    long i4 = (long)(b - g.blk0) * 256 + threadIdx.x;
    if (i4 >= g.total4) return;
    long i = i4 * 4;
    int r = (int)(i / g.dc), c0 = (int)(i % g.dc);
    us4 o;
#pragma unroll
    for (int e = 0; e < 4; ++e) {
        int c = c0 + e;
        float v = (r < g.sr && c < g.sc) ? g.src[(size_t)r * g.sld + c] : 0.f;
        o[e] = f2bf(v);
    }
    *(us4*)&g.dst[i] = o;
}

// ---------------- causal depthwise conv (width 4) + bias + silu ----------------
__global__ void k_conv_silu(const float* __restrict__ xz, const float* __restrict__ cw,
                            const float* __restrict__ cb, float* __restrict__ uc,
                            u16* __restrict__ ucb) {
    int d = blockIdx.x * 256 + threadIdx.x;   // 0..1535
    int r = blockIdx.y;                       // 0..2047
    int l = r & (SL - 1);
    float acc = cb[d];
#pragma unroll
    for (int j = 0; j < 4; ++j) {
        int ls = l - 3 + j;
        if (ls >= 0) acc += xz[(size_t)(r - 3 + j) * (2 * DI) + d] * cw[d * 4 + j];
    }
    float s = acc / (1.f + __expf(-acc));
    uc[(size_t)r * DI + d] = s;
    ucb[(size_t)r * DI + d] = f2bf(s);
}

// ------ split-K reduce for x_proj: part[2048][8*128] -> xdbl f32 + xdblb bf16 ------
__global__ __launch_bounds__(256)
void k_xp_red(const float* __restrict__ part, float* __restrict__ xdbl,
              u16* __restrict__ xdblb) {
    int idx = blockIdx.x * 256 + threadIdx.x;    // 2048*128
    int row = idx >> 7, col = idx & 127;
    const float* p = part + (size_t)row * 1024 + col;
    float s = 0.f;
#pragma unroll
    for (int k = 0; k < 8; ++k) s += p[k * 128];
    xdbl[(size_t)row * 128 + col] = s;
    if (col < 64) xdblb[(size_t)row * 64 + col] = f2bf(s);
}

// ---------------- chunked selective scan (8 chunks x 128 steps, 1 kernel) --------------
__global__ __launch_bounds__(512)
void k_scan2(const float* __restrict__ delta, const float* __restrict__ uc,
             const float* __restrict__ xdbl, const float* __restrict__ xz,
             const float* __restrict__ alog, const float* __restrict__ Dp,
             u16* __restrict__ ybf) {
    __shared__ float ds2[8][16][20], us2[8][16][20], bn2[8][16][20], cn2[8][16][20];
    __shared__ float Sm[8][16][16], Pm[8][16][16];
    int b  = blockIdx.x / 96;
    int d0 = (blockIdx.x % 96) * 16;
    int tid = threadIdx.x, w = tid >> 6, lane = tid & 63;
    int ch = lane >> 2, nq = lane & 3;
    int d = d0 + ch;
    float A[4];
#pragma unroll
    for (int k = 0; k < 4; ++k) A[k] = -__expf(alog[d * DSN + nq + 4 * k]);
    int tb = w * 128;

    // ---- phase 1 ----
    float h[4] = {0.f, 0.f, 0.f, 0.f};
    float sdl = 0.f;
    for (int t0 = 0; t0 < 128; t0 += 16) {
        int row0 = b * SL + tb + t0;
#pragma unroll
        for (int i = 0; i < 4; ++i) {
            int lin = i * 64 + lane, tt = lin >> 4, cc = lin & 15;
            size_t row = (size_t)(row0 + tt);
            ds2[w][cc][tt] = delta[row * DI + d0 + cc];
            us2[w][cc][tt] = uc[row * DI + d0 + cc];
            bn2[w][cc][tt] = xdbl[row * 128 + 48 + cc];
        }
#pragma unroll
        for (int g4 = 0; g4 < 4; ++g4) {
            f32x4 dl = *(const f32x4*)&ds2[w][ch][g4 * 4];
            f32x4 uv = *(const f32x4*)&us2[w][ch][g4 * 4];
            f32x4 bv[4];
#pragma unroll
            for (int k = 0; k < 4; ++k) bv[k] = *(const f32x4*)&bn2[w][nq + 4 * k][g4 * 4];
#pragma unroll
            for (int s = 0; s < 4; ++s) {
                float du = dl[s] * uv[s];
                sdl += dl[s];
#pragma unroll
                for (int k = 0; k < 4; ++k) {
                    float dA = __expf(dl[s] * A[k]);
                    h[k] = h[k] * dA + du * bv[k][s];
                }
            }
        }
    }
#pragma unroll
    for (int k = 0; k < 4; ++k) {
        Sm[w][ch][nq + 4 * k] = h[k];
        Pm[w][ch][nq + 4 * k] = __expf(A[k] * sdl);
    }
    __syncthreads();
    if (tid < 256) {
        int c2 = tid >> 4, n2 = tid & 15;
        float H = 0.f;
#pragma unroll
        for (int g = 0; g < 8; ++g) {
            float hi = H;
            H = Pm[g][c2][n2] * H + Sm[g][c2][n2];
            Sm[g][c2][n2] = hi;
        }
    }
    __syncthreads();
    // ---- phase 3 ----
    float Dv = Dp[d];
#pragma unroll
    for (int k = 0; k < 4; ++k) h[k] = Sm[w][ch][nq + 4 * k];
    for (int t0 = 0; t0 < 128; t0 += 16) {
        int row0 = b * SL + tb + t0;
#pragma unroll
        for (int i = 0; i < 4; ++i) {
            int lin = i * 64 + lane, tt = lin >> 4, cc = lin & 15;
            size_t row = (size_t)(row0 + tt);
            ds2[w][cc][tt] = delta[row * DI + d0 + cc];
            us2[w][cc][tt] = uc[row * DI + d0 + cc];
            bn2[w][cc][tt] = xdbl[row * 128 + 48 + cc];
            cn2[w][cc][tt] = xdbl[row * 128 + 64 + cc];
        }
#pragma unroll
        for (int g4 = 0; g4 < 4; ++g4) {
            f32x4 dl = *(const f32x4*)&ds2[w][ch][g4 * 4];
            f32x4 uv = *(const f32x4*)&us2[w][ch][g4 * 4];
            f32x4 bv[4], cv[4];
#pragma unroll
            for (int k = 0; k < 4; ++k) {
                bv[k] = *(const f32x4*)&bn2[w][nq + 4 * k][g4 * 4];
                cv[k] = *(const f32x4*)&cn2[w][nq + 4 * k][g4 * 4];
            }
#pragma unroll
            for (int s = 0; s < 4; ++s) {
                float du = dl[s] * uv[s];
                float p = 0.f;
#pragma unroll
                for (int k = 0; k < 4; ++k) {
                    float dA = __expf(dl[s] * A[k]);
                    h[k] = h[k] * dA + du * bv[k][s];
                    p += h[k] * cv[k][s];
                }
                p += __shfl_xor(p, 1);
                p += __shfl_xor(p, 2);
                if (nq == 0) {
                    size_t row = (size_t)(row0 + g4 * 4 + s);
                    float z = xz[row * (2 * DI) + DI + d];
                    float y = p + uv[s] * Dv;
                    y *= z / (1.f + __expf(-z));
                    ybf[row * DI + d] = f2bf(y);
                }
            }
        }
    }
}

// ------- 128^2 bf16 MFMA GEMM (layer GEMMs), fused epilogue, optional split-K ------
// EPIL: 0 = plain, 1 = add residual, 2 = softplus(v + bias[col])
// SPLITK: wg/nTm selects a K-slice; C cols offset by slice*128 (ldc = nslices*128).
template <int EPIL, bool SPLITK>
__global__ __launch_bounds__(256)
void k_gemm_bt(const u16* __restrict__ A, const u16* __restrict__ W,
               float* C, const float* RES,
               const float* __restrict__ BIASV,
               int K, int ldk, int ldc, int nTm) {
    __shared__ u16 Al[128 * 32];
    __shared__ u16 Wl[128 * 32];
    int nwg = gridDim.x;
    int qc = nwg >> 3, rc = nwg & 7;
    int xcd = blockIdx.x & 7, j = blockIdx.x >> 3;
    int wg = (xcd < rc ? xcd * (qc + 1) : rc * (qc + 1) + (xcd - rc) * qc) + j;
    int m0 = (wg % nTm) * 128;
    int sl = wg / nTm;
    int n0 = SPLITK ? 0 : sl * 128;        // W row base
    int cb = SPLITK ? sl * 128 : n0;       // C col base
    int kb = SPLITK ? sl * K : 0;          // K slice base

    int tid = threadIdx.x, wave = tid >> 6, lane = tid & 63;
    int wm = wave >> 1, wn = wave & 1;
    f32x4 acc[4][4] = {};
    const int rS = (lane >> 2);
    const int kS = (((lane & 3) ^ ((lane >> 3) & 3)) * 8);
    const int kofs = (((lane >> 4) ^ ((lane >> 1) & 3)) * 8);
    const int fr = lane & 15;

    for (int k0 = 0; k0 < K; k0 += 32) {
#pragma unroll
        for (int i = 0; i < 2; ++i) {
            int rowA = m0 + wave * 32 + i * 16 + rS;
            G_LDS16(A + (size_t)rowA * ldk + kb + k0 + kS, &Al[wave * 1024 + i * 512]);
            int rowW = n0 + wave * 32 + i * 16 + rS;
            G_LDS16(W + (size_t)rowW * ldk + kb + k0 + kS, &Wl[wave * 1024 + i * 512]);
        }
        __syncthreads();
        short8 af[4], bfr[4];
#pragma unroll
        for (int f = 0; f < 4; ++f) {
            af[f]  = *(const short8*)&Al[(wm * 64 + f * 16 + fr) * 32 + kofs];
            bfr[f] = *(const short8*)&Wl[(wn * 64 + f * 16 + fr) * 32 + kofs];
        }
#pragma unroll
        for (int i = 0; i < 4; ++i)
#pragma unroll
            for (int jj = 0; jj < 4; ++jj)
                acc[i][jj] = __builtin_amdgcn_mfma_f32_16x16x32_bf16(af[i], bfr[jj], acc[i][jj], 0, 0, 0);
        __syncthreads();
    }
    int r4 = (lane >> 4) * 4;
#pragma unroll
    for (int i = 0; i < 4; ++i)
#pragma unroll
        for (int jj = 0; jj < 4; ++jj) {
            int col = cb + wn * 64 + jj * 16 + fr;
            float bia = (EPIL == 2) ? BIASV[col] : 0.f;
#pragma unroll
            for (int rr = 0; rr < 4; ++rr) {
                int row = m0 + wm * 64 + i * 16 + r4 + rr;
                size_t off = (size_t)row * ldc + col;
                float v = acc[i][jj][rr];
                if (EPIL == 1) v += RES[off];
                if (EPIL == 2) { v += bia; v = (v > 20.f) ? v : log1pf(__expf(v)); }
                C[off] = v;
            }
        }
}

// ===== 256^2 4-phase bf16 GEMM (lm_head), BK=32 / 64 KiB LDS =====
// 512 thr = 8 waves (2M x 4N); per-wave 128x64 C; counted vmcnt(3);
// 4 phases per 2 K-tiles (16 MFMA/cluster) — barriers halved vs the 8-phase form,
// identical stage set and vmcnt cadence (invariant: tile t+1 landed, 3 of t+2 in flight).
// NOTE: launch_bounds MUST stay (512,2) — (512,4) caps VGPR at 64 and spills acc (r11).
#define BAR  __builtin_amdgcn_s_barrier()
#define LGK0 do { asm volatile("s_waitcnt lgkmcnt(0)" ::: "memory"); \
                  __builtin_amdgcn_sched_barrier(0); } while (0)
#define VMC3 asm volatile("s_waitcnt vmcnt(3)" ::: "memory")
#define VMC0 asm volatile("s_waitcnt vmcnt(0)" ::: "memory")

#define STAGE1(t, op, half, GB, RB) do {                                      \
    const u16* _g = (GB) + (size_t)((RB) + (half) * 128 + (w << 4) + srow) * K \
                    + (t) * 32 + scol;                                         \
    G_LDS16(_g, &lds[(t) & 1][op][half][w << 9]);                              \
} while (0)

#define RDA(dst, t, mq) do {                                                   \
    _Pragma("unroll") for (int _m = 0; _m < 4; ++_m)                           \
        dst[_m] = *(const short8*)&lds[(t) & 1][0][wm]                         \
            [((mq) * 64 + _m * 16 + fr) * 32 + rd_sw];                         \
} while (0)

#define RDB(t, nq) do {                                                       \
    _Pragma("unroll") for (int _n = 0; _n < 2; ++_n)                           \
        bfv[_n] = *(const short8*)&lds[(t) & 1][1][wbh]                        \
            [(wbr * 64 + (nq) * 32 + _n * 16 + fr) * 32 + rd_sw];              \
} while (0)

#define MM8(AF, mq, nq) do {                                                  \
    __builtin_amdgcn_s_setprio(1);                                            \
    _Pragma("unroll") for (int _m = 0; _m < 4; ++_m)                           \
    _Pragma("unroll") for (int _n = 0; _n < 2; ++_n)                           \
        acc[(mq) * 4 + _m][(nq) * 2 + _n] =                                    \
            __builtin_amdgcn_mfma_f32_16x16x32_bf16(                           \
                AF[_m], bfv[_n], acc[(mq) * 4 + _m][(nq) * 2 + _n], 0, 0, 0);  \
    __builtin_amdgcn_s_setprio(0);                                            \
} while (0)

template <int K>
__global__ __launch_bounds__(512, 2)
void k_gemm256(const u16* __restrict__ Ap, const u16* __restrict__ Wp,
               float* __restrict__ C, int ldc, int nmax, int nTm) {
    constexpr int NT = K / 32;       // 24 K-tiles (even, >= 4)
    constexpr int NI = NT / 2;       // 12 pair iterations
    __shared__ __align__(16) u16 lds[2][2][2][4096];  // 64 KiB: [buf][A/B][half][128x32]

    int per8 = gridDim.x >> 3;
    int wg = (blockIdx.x & 7) * per8 + (blockIdx.x >> 3);
    int m0 = (wg % nTm) * 256, n0 = (wg / nTm) * 256;

    int tid = threadIdx.x, w = tid >> 6, lane = tid & 63;
    int wm = w >> 2, wn = w & 3, wbh = wn >> 1, wbr = wn & 1;
    int fr = lane & 15;
    // proven 128^2 swizzle pair for [row][32] layout (64B row stride):
    int rd_sw = (((lane >> 4) ^ ((lane >> 1) & 3)) * 8);   // read col offset (elems)
    int srow  = lane >> 2;                                 // staging row 0..15
    int scol  = (((lane & 3) ^ ((lane >> 3) & 3)) * 8);    // pre-swizzled source col

    f32x4 acc[8][4] = {};
    short8 af0[4], af1[4], bfv[2];

    // ---- prologue: tile0 full + tile1 {A0,A1,B0}; 7 loads/wave; vmcnt(3) => tile0 ----
    STAGE1(0, 0, 0, Ap, m0); STAGE1(0, 0, 1, Ap, m0);
    STAGE1(0, 1, 0, Wp, n0); STAGE1(0, 1, 1, Wp, n0);
    STAGE1(1, 0, 0, Ap, m0); STAGE1(1, 0, 1, Ap, m0);
    STAGE1(1, 1, 0, Wp, n0);
    VMC3; BAR;

    // ---- main loop: 4 phases per 2 tiles; vmcnt(3) at phases 2 & 4 ----
    for (int i = 0; i < NI - 1; ++i) {
        const int ta = 2 * i, tb = 2 * i + 1;
        // P1
        RDA(af0, ta, 0); RDA(af1, ta, 1); RDB(ta, 0);
        STAGE1(tb, 1, 1, Wp, n0);
        STAGE1(ta + 2, 0, 0, Ap, m0);
        BAR; LGK0; MM8(af0, 0, 0); MM8(af1, 1, 0); BAR;
        // P2
        RDB(ta, 1);
        STAGE1(ta + 2, 0, 1, Ap, m0);
        STAGE1(ta + 2, 1, 0, Wp, n0);
        BAR; LGK0; MM8(af1, 1, 1); MM8(af0, 0, 1); VMC3; BAR;
        // P3
        RDA(af0, tb, 0); RDA(af1, tb, 1); RDB(tb, 0);
        STAGE1(ta + 2, 1, 1, Wp, n0);
        STAGE1(ta + 3, 0, 0, Ap, m0);
        BAR; LGK0; MM8(af0, 0, 0); MM8(af1, 1, 0); BAR;
        // P4
        RDB(tb, 1);
        STAGE1(ta + 3, 0, 1, Ap, m0);
        STAGE1(ta + 3, 1, 0, Wp, n0);
        BAR; LGK0; MM8(af1, 1, 1); MM8(af0, 0, 1); VMC3; BAR;
    }
    // ---- peeled last pair: only P1 stages (tb,B1); vmcnt(0) at P2 ----
    {
        const int ta = NT - 2, tb = NT - 1;
        RDA(af0, ta, 0); RDA(af1, ta, 1); RDB(ta, 0);
        STAGE1(tb, 1, 1, Wp, n0);
        BAR; LGK0; MM8(af0, 0, 0); MM8(af1, 1, 0); BAR;
        RDB(ta, 1);
        BAR; LGK0; MM8(af1, 1, 1); MM8(af0, 0, 1); VMC0; BAR;
        RDA(af0, tb, 0); RDA(af1, tb, 1); RDB(tb, 0);
        BAR; LGK0; MM8(af0, 0, 0); MM8(af1, 1, 0); BAR;
        RDB(tb, 1);
        BAR; LGK0; MM8(af1, 1, 1); MM8(af0, 0, 1); BAR;
    }

    // ---- epilogue: C write (registers only) ----
    int r4 = (lane >> 4) * 4;
#pragma unroll
    for (int mi = 0; mi < 8; ++mi)
#pragma unroll
        for (int ni = 0; ni < 4; ++ni) {
            int col = n0 + wn * 64 + (ni >> 1) * 32 + (ni & 1) * 16 + fr;
            if (col >= nmax) continue;
            int row = m0 + wm * 128 + (mi >> 2) * 64 + (mi & 3) * 16 + r4;
#pragma unroll
            for (int rr = 0; rr < 4; ++rr)
                C[(size_t)(row + rr) * ldc + col] = acc[mi][ni][rr];
        }
}

// ---------------- host ----------------
extern "C" void kernel_launch(void* const* d_in, const int* in_sizes, int n_in,
                              void* d_out, int out_size, void* d_ws, size_t ws_size,
                              hipStream_t stream) {
    (void)in_sizes; (void)n_in; (void)out_size;
    const int*   tok   = (const int*)d_in[0];
    const float* emb   = (const float*)d_in[1];
    const float* normw = (const float*)d_in[2];
    const float* inw   = (const float*)d_in[3];
    const float* cw    = (const float*)d_in[4];
    const float* cb    = (const float*)d_in[5];
    const float* xpw   = (const float*)d_in[6];
    const float* dtw   = (const float*)d_in[7];
    const float* dtb   = (const float*)d_in[8];
    const float* alog  = (const float*)d_in[9];
    const float* Dp    = (const float*)d_in[10];
    const float* outw  = (const float*)d_in[11];
    const float* normf = (const float*)d_in[12];
    const float* lmw   = (const float*)d_in[13];
    float* out = (float*)d_out;

    char* p = (char*)d_ws;
    auto alloc = [&](size_t bytes) { char* r = p; p += (bytes + 255) & ~(size_t)255; return r; };
    float* x     = (float*)alloc((size_t)MROWS * DM * 4);
    u16*   xnb   = (u16*)  alloc((size_t)MROWS * DM * 2);
    float* xz    = (float*)alloc((size_t)MROWS * 2 * DI * 4);
    float* uc    = (float*)alloc((size_t)MROWS * DI * 4);
    u16*   ucb   = (u16*)  alloc((size_t)MROWS * DI * 2);
    float* xdbl  = (float*)alloc((size_t)MROWS * 128 * 4);
    u16*   xdblb = (u16*)  alloc((size_t)MROWS * 64 * 2);
    float* part  = (float*)alloc((size_t)MROWS * 1024 * 4);   // x_proj split-K partials
    float* delta = (float*)alloc((size_t)MROWS * DI * 4);
    u16*   ybf   = (u16*)  alloc((size_t)MROWS * DI * 2);
    u16*   winb  = (u16*)  alloc((size_t)NB * (2 * DI) * DM * 2);
    u16*   wxpb  = (u16*)  alloc((size_t)NB * 128 * DI * 2);
    u16*   wdtb  = (u16*)  alloc((size_t)NB * DI * 64 * 2);
    u16*   woutb = (u16*)  alloc((size_t)NB * DM * DI * 2);
    u16*   wlmb  = (u16*)  alloc((size_t)VOCP * DM * 2);
    if ((size_t)(p - (char*)d_ws) > ws_size) return;  // insufficient scratch: fail loudly

    // ---- one fused weight-conversion launch (9 segments) ----
    CvtArgs ca;
    int blk = 0;
    auto seg = [&](int idx, const float* s, u16* d, int sr, int sc, int sld, int dc, int dr) {
        int t4 = dr * dc / 4;
        ca.seg[idx] = CvtSeg{s, d, sr, sc, sld, dc, blk, t4};
        blk += (t4 + 255) / 256;
    };
    seg(0, lmw, wlmb, VOC, DM, DM, DM, VOCP);
    seg(1, inw,                          winb,                          2 * DI, DM, DM, DM, 2 * DI);
    seg(2, inw + (size_t)2 * DI * DM,    winb + (size_t)2 * DI * DM,    2 * DI, DM, DM, DM, 2 * DI);
    seg(3, xpw,                          wxpb,                          80, DI, DI, DI, 128);
    seg(4, xpw + (size_t)80 * DI,        wxpb + (size_t)128 * DI,       80, DI, DI, DI, 128);
    seg(5, dtw,                          wdtb,                          DI, 48, 48, 64, DI);
    seg(6, dtw + (size_t)DI * 48,        wdtb + (size_t)DI * 64,        DI, 48, 48, 64, DI);
    seg(7, outw,                         woutb,                         DM, DI, DI, DI, DM);
    seg(8, outw + (size_t)DM * DI,       woutb + (size_t)DM * DI,       DM, DI, DI, DI, DM);
    k_cvt_multi<<<dim3(blk), 256, 0, stream>>>(ca);

    // embedding + layer-0 rmsnorm fused
    k_embed_rms<<<MROWS, 256, 0, stream>>>(tok, emb, normw, x, xnb);

    for (int i = 0; i < NB; ++i) {
        if (i > 0)
            k_rmsnorm_bf16<<<MROWS, 256, 0, stream>>>(x, normw + i * DM, xnb);

        k_gemm_bt<0, false><<<dim3(16 * (2 * DI / 128)), 256, 0, stream>>>(
            xnb, winb + (size_t)i * 2 * DI * DM, xz, nullptr, nullptr,
            DM, DM, 2 * DI, 16);

        k_conv_silu<<<dim3(DI / 256, MROWS), 256, 0, stream>>>(
            xz, cw + (size_t)i * DI * 4, cb + (size_t)i * DI, uc, ucb);

        // x_proj (N=128) split-K x8: 128 blocks, partials [2048][8*128]
        k_gemm_bt<0, true><<<dim3(16 * 8), 256, 0, stream>>>(
            ucb, wxpb + (size_t)i * 128 * DI, part, nullptr, nullptr,
            DI / 8, DI, 1024, 16);
        k_xp_red<<<dim3(MROWS * 128 / 256), 256, 0, stream>>>(part, xdbl, xdblb);

        // dt GEMM (K=64) with fused softplus(v + dt_bias) -> delta
        k_gemm_bt<2, false><<<dim3(16 * (DI / 128)), 256, 0, stream>>>(
            xdblb, wdtb + (size_t)i * DI * 64, delta, nullptr, dtb + (size_t)i * DI,
            64, 64, DI, 16);

        k_scan2<<<dim3(NB * (DI / 16)), 512, 0, stream>>>(
            delta, uc, xdbl, xz, alog + (size_t)i * DI * DSN, Dp + i * DI, ybf);

        // out_proj (N=768) with fused residual add
        k_gemm_bt<1, false><<<dim3(16 * (DM / 128)), 256, 0, stream>>>(
            ybf, woutb + (size_t)i * DM * DI, x, x, nullptr, DI, DI, DM, 16);
    }

    k_rmsnorm_bf16<<<MROWS, 256, 0, stream>>>(x, normf, xnb);
    k_gemm256<DM><<<dim3(8 * (VOCP / 256)), 512, 0, stream>>>(
        xnb, wlmb, out, VOC, VOC, 8);
}

// Round 14
// 737.889 us; speedup vs baseline: 3.3700x; 1.0133x over previous
//
#include <hip/hip_runtime.h>
#include <hip/hip_bf16.h>
#include <math.h>

#define DM 768
#define DI 1536
#define DSN 16
#define NB 2
#define SL 1024
#define MROWS 2048
#define VOC 50257
#define VOCP 50432           // padded to multiple of 256 for the 256^2 lm_head GEMM
#define EPSR 1e-5f

typedef __attribute__((ext_vector_type(8))) short short8;
typedef __attribute__((ext_vector_type(4))) float f32x4;
typedef __attribute__((ext_vector_type(4))) unsigned short us4;
typedef unsigned short u16;

__device__ inline u16 f2bf(float f) {
    unsigned u = __builtin_bit_cast(unsigned, f);
    u += 0x7FFFu + ((u >> 16) & 1u);   // round-to-nearest-even
    return (u16)(u >> 16);
}

#define G_LDS16(g, l) __builtin_amdgcn_global_load_lds( \
    (const __attribute__((address_space(1))) void*)(g), \
    (__attribute__((address_space(3))) void*)(l), 16, 0, 0)

// ---------------- embedding gather + layer-0 RMSNorm (fused) ----------------
__global__ __launch_bounds__(256)
void k_embed_rms(const int* __restrict__ tok, const float* __restrict__ emb,
                 const float* __restrict__ w, float* __restrict__ x,
                 u16* __restrict__ out) {
    int r = blockIdx.x;
    int t = tok[r];
    const float* src = emb + (size_t)t * DM;
    int c0 = threadIdx.x * 3;
    float v[3]; float ss = 0.f;
#pragma unroll
    for (int i = 0; i < 3; ++i) {
        v[i] = src[c0 + i]; ss += v[i] * v[i];
        x[(size_t)r * DM + c0 + i] = v[i];
    }
#pragma unroll
    for (int o = 32; o > 0; o >>= 1) ss += __shfl_down(ss, o);
    __shared__ float s[4];
    int lane = threadIdx.x & 63, wv = threadIdx.x >> 6;
    if (lane == 0) s[wv] = ss;
    __syncthreads();
    float sc = rsqrtf((s[0] + s[1] + s[2] + s[3]) / (float)DM + EPSR);
#pragma unroll
    for (int i = 0; i < 3; ++i)
        out[(size_t)r * DM + c0 + i] = f2bf(v[i] * sc * w[c0 + i]);
}

// ---------------- RMSNorm -> bf16 ----------------
__global__ __launch_bounds__(256)
void k_rmsnorm_bf16(const float* __restrict__ x, const float* __restrict__ w,
                    u16* __restrict__ out) {
    int r = blockIdx.x;
    const float* row = x + (size_t)r * DM;
    int c0 = threadIdx.x * 3;
    float v[3]; float ss = 0.f;
#pragma unroll
    for (int i = 0; i < 3; ++i) { v[i] = row[c0 + i]; ss += v[i] * v[i]; }
#pragma unroll
    for (int o = 32; o > 0; o >>= 1) ss += __shfl_down(ss, o);
    __shared__ float s[4];
    int lane = threadIdx.x & 63, wv = threadIdx.x >> 6;
    if (lane == 0) s[wv] = ss;
    __syncthreads();
    float sc = rsqrtf((s[0] + s[1] + s[2] + s[3]) / (float)DM + EPSR);
#pragma unroll
    for (int i = 0; i < 3; ++i)
        out[(size_t)r * DM + c0 + i] = f2bf(v[i] * sc * w[c0 + i]);
}

// -------- fused multi-segment f32 -> bf16 weight conversion (one launch) --------
struct CvtSeg { const float* src; u16* dst; int sr, sc, sld, dc, blk0, total4; };
struct CvtArgs { CvtSeg seg[9]; };

__global__ __launch_bounds__(256)
void k_cvt_multi(CvtArgs a) {
    int b = blockIdx.x;
    int s = 0;
#pragma unroll
    for (int q = 1; q < 9; ++q) if (a.seg[q].blk0 <= b) s = q;
    const CvtSeg& g = a.seg[s];
    long i4 = (long)(b - g.blk0) * 256 + threadIdx.x;
    if (i4 >= g.total4) return;
    long i = i4 * 4;
    int r = (int)(i / g.dc), c0 = (int)(i % g.dc);
    us4 o;
#pragma unroll
    for (int e = 0; e < 4; ++e) {
        int c = c0 + e;
        float v = (r < g.sr && c < g.sc) ? g.src[(size_t)r * g.sld + c] : 0.f;
        o[e] = f2bf(v);
    }
    *(us4*)&g.dst[i] = o;
}

// ---------------- causal depthwise conv (width 4) + bias + silu ----------------
__global__ void k_conv_silu(const float* __restrict__ xz, const float* __restrict__ cw,
                            const float* __restrict__ cb, float* __restrict__ uc,
                            u16* __restrict__ ucb) {
    int d = blockIdx.x * 256 + threadIdx.x;   // 0..1535
    int r = blockIdx.y;                       // 0..2047
    int l = r & (SL - 1);
    float acc = cb[d];
#pragma unroll
    for (int j = 0; j < 4; ++j) {
        int ls = l - 3 + j;
        if (ls >= 0) acc += xz[(size_t)(r - 3 + j) * (2 * DI) + d] * cw[d * 4 + j];
    }
    float s = acc / (1.f + __expf(-acc));
    uc[(size_t)r * DI + d] = s;
    ucb[(size_t)r * DI + d] = f2bf(s);
}

// ------ split-K reduce for x_proj: part[2048][8*128] -> xdbl f32 + xdblb bf16 ------
__global__ __launch_bounds__(256)
void k_xp_red(const float* __restrict__ part, float* __restrict__ xdbl,
              u16* __restrict__ xdblb) {
    int idx = blockIdx.x * 256 + threadIdx.x;    // 2048*128
    int row = idx >> 7, col = idx & 127;
    const float* p = part + (size_t)row * 1024 + col;
    float s = 0.f;
#pragma unroll
    for (int k = 0; k < 8; ++k) s += p[k * 128];
    xdbl[(size_t)row * 128 + col] = s;
    if (col < 64) xdblb[(size_t)row * 64 + col] = f2bf(s);
}

// ---------------- chunked selective scan (8 chunks x 128 steps, 1 kernel) --------------
__global__ __launch_bounds__(512)
void k_scan2(const float* __restrict__ delta, const float* __restrict__ uc,
             const float* __restrict__ xdbl, const float* __restrict__ xz,
             const float* __restrict__ alog, const float* __restrict__ Dp,
             u16* __restrict__ ybf) {
    __shared__ float ds2[8][16][20], us2[8][16][20], bn2[8][16][20], cn2[8][16][20];
    __shared__ float Sm[8][16][16], Pm[8][16][16];
    int b  = blockIdx.x / 96;
    int d0 = (blockIdx.x % 96) * 16;
    int tid = threadIdx.x, w = tid >> 6, lane = tid & 63;
    int ch = lane >> 2, nq = lane & 3;
    int d = d0 + ch;
    float A[4];
#pragma unroll
    for (int k = 0; k < 4; ++k) A[k] = -__expf(alog[d * DSN + nq + 4 * k]);
    int tb = w * 128;

    // ---- phase 1 ----
    float h[4] = {0.f, 0.f, 0.f, 0.f};
    float sdl = 0.f;
    for (int t0 = 0; t0 < 128; t0 += 16) {
        int row0 = b * SL + tb + t0;
#pragma unroll
        for (int i = 0; i < 4; ++i) {
            int lin = i * 64 + lane, tt = lin >> 4, cc = lin & 15;
            size_t row = (size_t)(row0 + tt);
            ds2[w][cc][tt] = delta[row * DI + d0 + cc];
            us2[w][cc][tt] = uc[row * DI + d0 + cc];
            bn2[w][cc][tt] = xdbl[row * 128 + 48 + cc];
        }
#pragma unroll
        for (int g4 = 0; g4 < 4; ++g4) {
            f32x4 dl = *(const f32x4*)&ds2[w][ch][g4 * 4];
            f32x4 uv = *(const f32x4*)&us2[w][ch][g4 * 4];
            f32x4 bv[4];
#pragma unroll
            for (int k = 0; k < 4; ++k) bv[k] = *(const f32x4*)&bn2[w][nq + 4 * k][g4 * 4];
#pragma unroll
            for (int s = 0; s < 4; ++s) {
                float du = dl[s] * uv[s];
                sdl += dl[s];
#pragma unroll
                for (int k = 0; k < 4; ++k) {
                    float dA = __expf(dl[s] * A[k]);
                    h[k] = h[k] * dA + du * bv[k][s];
                }
            }
        }
    }
#pragma unroll
    for (int k = 0; k < 4; ++k) {
        Sm[w][ch][nq + 4 * k] = h[k];
        Pm[w][ch][nq + 4 * k] = __expf(A[k] * sdl);
    }
    __syncthreads();
    if (tid < 256) {
        int c2 = tid >> 4, n2 = tid & 15;
        float H = 0.f;
#pragma unroll
        for (int g = 0; g < 8; ++g) {
            float hi = H;
            H = Pm[g][c2][n2] * H + Sm[g][c2][n2];
            Sm[g][c2][n2] = hi;
        }
    }
    __syncthreads();
    // ---- phase 3 ----
    float Dv = Dp[d];
#pragma unroll
    for (int k = 0; k < 4; ++k) h[k] = Sm[w][ch][nq + 4 * k];
    for (int t0 = 0; t0 < 128; t0 += 16) {
        int row0 = b * SL + tb + t0;
#pragma unroll
        for (int i = 0; i < 4; ++i) {
            int lin = i * 64 + lane, tt = lin >> 4, cc = lin & 15;
            size_t row = (size_t)(row0 + tt);
            ds2[w][cc][tt] = delta[row * DI + d0 + cc];
            us2[w][cc][tt] = uc[row * DI + d0 + cc];
            bn2[w][cc][tt] = xdbl[row * 128 + 48 + cc];
            cn2[w][cc][tt] = xdbl[row * 128 + 64 + cc];
        }
#pragma unroll
        for (int g4 = 0; g4 < 4; ++g4) {
            f32x4 dl = *(const f32x4*)&ds2[w][ch][g4 * 4];
            f32x4 uv = *(const f32x4*)&us2[w][ch][g4 * 4];
            f32x4 bv[4], cv[4];
#pragma unroll
            for (int k = 0; k < 4; ++k) {
                bv[k] = *(const f32x4*)&bn2[w][nq + 4 * k][g4 * 4];
                cv[k] = *(const f32x4*)&cn2[w][nq + 4 * k][g4 * 4];
            }
#pragma unroll
            for (int s = 0; s < 4; ++s) {
                float du = dl[s] * uv[s];
                float p = 0.f;
#pragma unroll
                for (int k = 0; k < 4; ++k) {
                    float dA = __expf(dl[s] * A[k]);
                    h[k] = h[k] * dA + du * bv[k][s];
                    p += h[k] * cv[k][s];
                }
                p += __shfl_xor(p, 1);
                p += __shfl_xor(p, 2);
                if (nq == 0) {
                    size_t row = (size_t)(row0 + g4 * 4 + s);
                    float z = xz[row * (2 * DI) + DI + d];
                    float y = p + uv[s] * Dv;
                    y *= z / (1.f + __expf(-z));
                    ybf[row * DI + d] = f2bf(y);
                }
            }
        }
    }
}

// ------- 128^2 bf16 MFMA GEMM (layer GEMMs), fused epilogue, optional split-K ------
// EPIL: 0 = plain, 1 = add residual, 2 = softplus(v + bias[col])
// SPLITK: wg/nTm selects a K-slice; C cols offset by slice*128 (ldc = nslices*128).
template <int EPIL, bool SPLITK>
__global__ __launch_bounds__(256)
void k_gemm_bt(const u16* __restrict__ A, const u16* __restrict__ W,
               float* C, const float* RES,
               const float* __restrict__ BIASV,
               int K, int ldk, int ldc, int nTm) {
    __shared__ u16 Al[128 * 32];
    __shared__ u16 Wl[128 * 32];
    int nwg = gridDim.x;
    int qc = nwg >> 3, rc = nwg & 7;
    int xcd = blockIdx.x & 7, j = blockIdx.x >> 3;
    int wg = (xcd < rc ? xcd * (qc + 1) : rc * (qc + 1) + (xcd - rc) * qc) + j;
    int m0 = (wg % nTm) * 128;
    int sl = wg / nTm;
    int n0 = SPLITK ? 0 : sl * 128;        // W row base
    int cb = SPLITK ? sl * 128 : n0;       // C col base
    int kb = SPLITK ? sl * K : 0;          // K slice base

    int tid = threadIdx.x, wave = tid >> 6, lane = tid & 63;
    int wm = wave >> 1, wn = wave & 1;
    f32x4 acc[4][4] = {};
    const int rS = (lane >> 2);
    const int kS = (((lane & 3) ^ ((lane >> 3) & 3)) * 8);
    const int kofs = (((lane >> 4) ^ ((lane >> 1) & 3)) * 8);
    const int fr = lane & 15;

    for (int k0 = 0; k0 < K; k0 += 32) {
#pragma unroll
        for (int i = 0; i < 2; ++i) {
            int rowA = m0 + wave * 32 + i * 16 + rS;
            G_LDS16(A + (size_t)rowA * ldk + kb + k0 + kS, &Al[wave * 1024 + i * 512]);
            int rowW = n0 + wave * 32 + i * 16 + rS;
            G_LDS16(W + (size_t)rowW * ldk + kb + k0 + kS, &Wl[wave * 1024 + i * 512]);
        }
        __syncthreads();
        short8 af[4], bfr[4];
#pragma unroll
        for (int f = 0; f < 4; ++f) {
            af[f]  = *(const short8*)&Al[(wm * 64 + f * 16 + fr) * 32 + kofs];
            bfr[f] = *(const short8*)&Wl[(wn * 64 + f * 16 + fr) * 32 + kofs];
        }
#pragma unroll
        for (int i = 0; i < 4; ++i)
#pragma unroll
            for (int jj = 0; jj < 4; ++jj)
                acc[i][jj] = __builtin_amdgcn_mfma_f32_16x16x32_bf16(af[i], bfr[jj], acc[i][jj], 0, 0, 0);
        __syncthreads();
    }
    int r4 = (lane >> 4) * 4;
#pragma unroll
    for (int i = 0; i < 4; ++i)
#pragma unroll
        for (int jj = 0; jj < 4; ++jj) {
            int col = cb + wn * 64 + jj * 16 + fr;
            float bia = (EPIL == 2) ? BIASV[col] : 0.f;
#pragma unroll
            for (int rr = 0; rr < 4; ++rr) {
                int row = m0 + wm * 64 + i * 16 + r4 + rr;
                size_t off = (size_t)row * ldc + col;
                float v = acc[i][jj][rr];
                if (EPIL == 1) v += RES[off];
                if (EPIL == 2) { v += bia; v = (v > 20.f) ? v : log1pf(__expf(v)); }
                C[off] = v;
            }
        }
}

// ===== 256^2 bf16 GEMM (lm_head): 3-buffer race-free pipeline, BK=32, 96 KiB LDS =====
// 512 thr = 8 waves (2M x 4N); 2 phases per K-tile; stage tile t+2 into buf[(t+2)%3]
// (= tile t-1's buffer, whose reads are lgkm-complete before the preceding barrier);
// counted vmcnt(4) once per tile keeps 8 loads/wave in flight (2 tiles of lookahead).
// NOTE: launch_bounds MUST stay (512,2) — (512,4) caps VGPR at 64 and spills acc (r11).
#define BAR  __builtin_amdgcn_s_barrier()
#define LGK0 do { asm volatile("s_waitcnt lgkmcnt(0)" ::: "memory"); \
                  __builtin_amdgcn_sched_barrier(0); } while (0)
#define VMC4 asm volatile("s_waitcnt vmcnt(4)" ::: "memory")
#define VMC0 asm volatile("s_waitcnt vmcnt(0)" ::: "memory")

// stage one half-tile (8 KB): each wave ONE global_load_lds of 1 KB (16 rows x 32)
#define STG(t, b, op, half, GB, RB) do {                                       \
    const u16* _g = (GB) + (size_t)((RB) + (half) * 128 + (w << 4) + srow) * K \
                    + (t) * 32 + scol;                                         \
    G_LDS16(_g, &lds[b][op][half][w << 9]);                                    \
} while (0)

#define RDA(dst, b, mq) do {                                                   \
    _Pragma("unroll") for (int _m = 0; _m < 4; ++_m)                           \
        dst[_m] = *(const short8*)&lds[b][0][wm]                               \
            [((mq) * 64 + _m * 16 + fr) * 32 + rd_sw];                         \
} while (0)

#define RDB(b, nq) do {                                                       \
    _Pragma("unroll") for (int _n = 0; _n < 2; ++_n)                           \
        bfv[_n] = *(const short8*)&lds[b][1][wbh]                              \
            [(wbr * 64 + (nq) * 32 + _n * 16 + fr) * 32 + rd_sw];              \
} while (0)

#define MM8(AF, mq, nq) do {                                                  \
    __builtin_amdgcn_s_setprio(1);                                            \
    _Pragma("unroll") for (int _m = 0; _m < 4; ++_m)                           \
    _Pragma("unroll") for (int _n = 0; _n < 2; ++_n)                           \
        acc[(mq) * 4 + _m][(nq) * 2 + _n] =                                    \
            __builtin_amdgcn_mfma_f32_16x16x32_bf16(                           \
                AF[_m], bfv[_n], acc[(mq) * 4 + _m][(nq) * 2 + _n], 0, 0, 0);  \
    __builtin_amdgcn_s_setprio(0);                                            \
} while (0)

// one K-tile: STAGE_ON: stage tile t+2 into buf bS; WAIT: 0=vmcnt4, 1=vmcnt0, 2=none
#define TILE(t, bR, bS, STAGE_ON, WAIT) do {                                   \
    /* P1 */                                                                   \
    RDA(af0, bR, 0); RDA(af1, bR, 1); RDB(bR, 0);                              \
    if (STAGE_ON) { STG((t) + 2, bS, 0, 0, Ap, m0);                            \
                    STG((t) + 2, bS, 0, 1, Ap, m0); }                          \
    BAR; LGK0; MM8(af0, 0, 0); MM8(af1, 1, 0); BAR;                            \
    /* P2 */                                                                   \
    RDB(bR, 1);                                                                \
    if (STAGE_ON) { STG((t) + 2, bS, 1, 0, Wp, n0);                            \
                    STG((t) + 2, bS, 1, 1, Wp, n0); }                          \
    BAR; LGK0; MM8(af1, 1, 1); MM8(af0, 0, 1);                                 \
    if ((WAIT) == 0) { VMC4; } else if ((WAIT) == 1) { VMC0; }                 \
    BAR;                                                                       \
} while (0)

template <int K>
__global__ __launch_bounds__(512, 2)
void k_gemm256(const u16* __restrict__ Ap, const u16* __restrict__ Wp,
               float* __restrict__ C, int ldc, int nmax, int nTm) {
    constexpr int NT = K / 32;       // 24 K-tiles (multiple of 3, >= 6)
    static_assert(NT % 3 == 0 && NT >= 6, "NT must be a multiple of 3");
    __shared__ __align__(16) u16 lds[3][2][2][4096];  // 96 KiB: [buf][A/B][half][128x32]

    int per8 = gridDim.x >> 3;
    int wg = (blockIdx.x & 7) * per8 + (blockIdx.x >> 3);
    int m0 = (wg % nTm) * 256, n0 = (wg / nTm) * 256;

    int tid = threadIdx.x, w = tid >> 6, lane = tid & 63;
    int wm = w >> 2, wn = w & 3, wbh = wn >> 1, wbr = wn & 1;
    int fr = lane & 15;
    // proven swizzle pair for [row][32] layout (64B row stride):
    int rd_sw = (((lane >> 4) ^ ((lane >> 1) & 3)) * 8);   // read col offset (elems)
    int srow  = lane >> 2;                                 // staging row 0..15
    int scol  = (((lane & 3) ^ ((lane >> 3) & 3)) * 8);    // pre-swizzled source col

    f32x4 acc[8][4] = {};
    short8 af0[4], af1[4], bfv[2];

    // ---- prologue: stage tiles 0 and 1 (8 loads/wave); vmcnt(4) => tile0 landed ----
    STG(0, 0, 0, 0, Ap, m0); STG(0, 0, 0, 1, Ap, m0);
    STG(0, 0, 1, 0, Wp, n0); STG(0, 0, 1, 1, Wp, n0);
    STG(1, 1, 0, 0, Ap, m0); STG(1, 1, 0, 1, Ap, m0);
    STG(1, 1, 1, 0, Wp, n0); STG(1, 1, 1, 1, Wp, n0);
    VMC4; BAR;

    // ---- main: triples of tiles, static buffer indices; stage t+2, wait t+1 ----
    for (int j = 0; j < NT / 3 - 1; ++j) {
        const int t0 = 3 * j;
        TILE(t0,     0, 2, 1, 0);
        TILE(t0 + 1, 1, 0, 1, 0);
        TILE(t0 + 2, 2, 1, 1, 0);
    }
    // ---- last triple: tiles NT-3 (stage NT-1), NT-2 (drain), NT-1 (pure) ----
    TILE(NT - 3, 0, 2, 1, 0);
    TILE(NT - 2, 1, 0, 0, 1);
    TILE(NT - 1, 2, 0, 0, 2);

    // ---- epilogue: C write (registers only) ----
    int r4 = (lane >> 4) * 4;
#pragma unroll
    for (int mi = 0; mi < 8; ++mi)
#pragma unroll
        for (int ni = 0; ni < 4; ++ni) {
            int col = n0 + wn * 64 + (ni >> 1) * 32 + (ni & 1) * 16 + fr;
            if (col >= nmax) continue;
            int row = m0 + wm * 128 + (mi >> 2) * 64 + (mi & 3) * 16 + r4;
#pragma unroll
            for (int rr = 0; rr < 4; ++rr)
                C[(size_t)(row + rr) * ldc + col] = acc[mi][ni][rr];
        }
}

// ---------------- host ----------------
extern "C" void kernel_launch(void* const* d_in, const int* in_sizes, int n_in,
                              void* d_out, int out_size, void* d_ws, size_t ws_size,
                              hipStream_t stream) {
    (void)in_sizes; (void)n_in; (void)out_size;
    const int*   tok   = (const int*)d_in[0];
    const float* emb   = (const float*)d_in[1];
    const float* normw = (const float*)d_in[2];
    const float* inw   = (const float*)d_in[3];
    const float* cw    = (const float*)d_in[4];
    const float* cb    = (const float*)d_in[5];
    const float* xpw   = (const float*)d_in[6];
    const float* dtw   = (const float*)d_in[7];
    const float* dtb   = (const float*)d_in[8];
    const float* alog  = (const float*)d_in[9];
    const float* Dp    = (const float*)d_in[10];
    const float* outw  = (const float*)d_in[11];
    const float* normf = (const float*)d_in[12];
    const float* lmw   = (const float*)d_in[13];
    float* out = (float*)d_out;

    char* p = (char*)d_ws;
    auto alloc = [&](size_t bytes) { char* r = p; p += (bytes + 255) & ~(size_t)255; return r; };
    float* x     = (float*)alloc((size_t)MROWS * DM * 4);
    u16*   xnb   = (u16*)  alloc((size_t)MROWS * DM * 2);
    float* xz    = (float*)alloc((size_t)MROWS * 2 * DI * 4);
    float* uc    = (float*)alloc((size_t)MROWS * DI * 4);
    u16*   ucb   = (u16*)  alloc((size_t)MROWS * DI * 2);
    float* xdbl  = (float*)alloc((size_t)MROWS * 128 * 4);
    u16*   xdblb = (u16*)  alloc((size_t)MROWS * 64 * 2);
    float* part  = (float*)alloc((size_t)MROWS * 1024 * 4);   // x_proj split-K partials
    float* delta = (float*)alloc((size_t)MROWS * DI * 4);
    u16*   ybf   = (u16*)  alloc((size_t)MROWS * DI * 2);
    u16*   winb  = (u16*)  alloc((size_t)NB * (2 * DI) * DM * 2);
    u16*   wxpb  = (u16*)  alloc((size_t)NB * 128 * DI * 2);
    u16*   wdtb  = (u16*)  alloc((size_t)NB * DI * 64 * 2);
    u16*   woutb = (u16*)  alloc((size_t)NB * DM * DI * 2);
    u16*   wlmb  = (u16*)  alloc((size_t)VOCP * DM * 2);
    if ((size_t)(p - (char*)d_ws) > ws_size) return;  // insufficient scratch: fail loudly

    // ---- one fused weight-conversion launch (9 segments) ----
    CvtArgs ca;
    int blk = 0;
    auto seg = [&](int idx, const float* s, u16* d, int sr, int sc, int sld, int dc, int dr) {
        int t4 = dr * dc / 4;
        ca.seg[idx] = CvtSeg{s, d, sr, sc, sld, dc, blk, t4};
        blk += (t4 + 255) / 256;
    };
    seg(0, lmw, wlmb, VOC, DM, DM, DM, VOCP);
    seg(1, inw,                          winb,                          2 * DI, DM, DM, DM, 2 * DI);
    seg(2, inw + (size_t)2 * DI * DM,    winb + (size_t)2 * DI * DM,    2 * DI, DM, DM, DM, 2 * DI);
    seg(3, xpw,                          wxpb,                          80, DI, DI, DI, 128);
    seg(4, xpw + (size_t)80 * DI,        wxpb + (size_t)128 * DI,       80, DI, DI, DI, 128);
    seg(5, dtw,                          wdtb,                          DI, 48, 48, 64, DI);
    seg(6, dtw + (size_t)DI * 48,        wdtb + (size_t)DI * 64,        DI, 48, 48, 64, DI);
    seg(7, outw,                         woutb,                         DM, DI, DI, DI, DM);
    seg(8, outw + (size_t)DM * DI,       woutb + (size_t)DM * DI,       DM, DI, DI, DI, DM);
    k_cvt_multi<<<dim3(blk), 256, 0, stream>>>(ca);

    // embedding + layer-0 rmsnorm fused
    k_embed_rms<<<MROWS, 256, 0, stream>>>(tok, emb, normw, x, xnb);

    for (int i = 0; i < NB; ++i) {
        if (i > 0)
            k_rmsnorm_bf16<<<MROWS, 256, 0, stream>>>(x, normw + i * DM, xnb);

        k_gemm_bt<0, false><<<dim3(16 * (2 * DI / 128)), 256, 0, stream>>>(
            xnb, winb + (size_t)i * 2 * DI * DM, xz, nullptr, nullptr,
            DM, DM, 2 * DI, 16);

        k_conv_silu<<<dim3(DI / 256, MROWS), 256, 0, stream>>>(
            xz, cw + (size_t)i * DI * 4, cb + (size_t)i * DI, uc, ucb);

        // x_proj (N=128) split-K x8: 128 blocks, partials [2048][8*128]
        k_gemm_bt<0, true><<<dim3(16 * 8), 256, 0, stream>>>(
            ucb, wxpb + (size_t)i * 128 * DI, part, nullptr, nullptr,
            DI / 8, DI, 1024, 16);
        k_xp_red<<<dim3(MROWS * 128 / 256), 256, 0, stream>>>(part, xdbl, xdblb);

        // dt GEMM (K=64) with fused softplus(v + dt_bias) -> delta
        k_gemm_bt<2, false><<<dim3(16 * (DI / 128)), 256, 0, stream>>>(
            xdblb, wdtb + (size_t)i * DI * 64, delta, nullptr, dtb + (size_t)i * DI,
            64, 64, DI, 16);

        k_scan2<<<dim3(NB * (DI / 16)), 512, 0, stream>>>(
            delta, uc, xdbl, xz, alog + (size_t)i * DI * DSN, Dp + i * DI, ybf);

        // out_proj (N=768) with fused residual add
        k_gemm_bt<1, false><<<dim3(16 * (DM / 128)), 256, 0, stream>>>(
            ybf, woutb + (size_t)i * DM * DI, x, x, nullptr, DI, DI, DM, 16);
    }

    k_rmsnorm_bf16<<<MROWS, 256, 0, stream>>>(x, normf, xnb);
    k_gemm256<DM><<<dim3(8 * (VOCP / 256)), 512, 0, stream>>>(
        xnb, wlmb, out, VOC, VOC, 8);
}

// Round 15
// 729.067 us; speedup vs baseline: 3.4108x; 1.0121x over previous
//
#include <hip/hip_runtime.h>
#include <hip/hip_bf16.h>
#include <math.h>

#define DM 768
#define DI 1536
#define DSN 16
#define NB 2
#define SL 1024
#define MROWS 2048
#define VOC 50257
#define VOCP 50432           // padded to multiple of 256 for the 256^2 lm_head GEMM
#define EPSR 1e-5f

typedef __attribute__((ext_vector_type(8))) short short8;
typedef __attribute__((ext_vector_type(4))) float f32x4;
typedef __attribute__((ext_vector_type(4))) unsigned short us4;
typedef unsigned short u16;

__device__ inline u16 f2bf(float f) {
    unsigned u = __builtin_bit_cast(unsigned, f);
    u += 0x7FFFu + ((u >> 16) & 1u);   // round-to-nearest-even
    return (u16)(u >> 16);
}
__device__ inline float bf2f(u16 v) {
    unsigned u = (unsigned)v << 16;
    return __builtin_bit_cast(float, u);
}

#define G_LDS16(g, l) __builtin_amdgcn_global_load_lds( \
    (const __attribute__((address_space(1))) void*)(g), \
    (__attribute__((address_space(3))) void*)(l), 16, 0, 0)

// ---------------- embedding gather + layer-0 RMSNorm (fused) ----------------
__global__ __launch_bounds__(256)
void k_embed_rms(const int* __restrict__ tok, const float* __restrict__ emb,
                 const float* __restrict__ w, float* __restrict__ x,
                 u16* __restrict__ out) {
    int r = blockIdx.x;
    int t = tok[r];
    const float* src = emb + (size_t)t * DM;
    int c0 = threadIdx.x * 3;
    float v[3]; float ss = 0.f;
#pragma unroll
    for (int i = 0; i < 3; ++i) {
        v[i] = src[c0 + i]; ss += v[i] * v[i];
        x[(size_t)r * DM + c0 + i] = v[i];
    }
#pragma unroll
    for (int o = 32; o > 0; o >>= 1) ss += __shfl_down(ss, o);
    __shared__ float s[4];
    int lane = threadIdx.x & 63, wv = threadIdx.x >> 6;
    if (lane == 0) s[wv] = ss;
    __syncthreads();
    float sc = rsqrtf((s[0] + s[1] + s[2] + s[3]) / (float)DM + EPSR);
#pragma unroll
    for (int i = 0; i < 3; ++i)
        out[(size_t)r * DM + c0 + i] = f2bf(v[i] * sc * w[c0 + i]);
}

// ---------------- RMSNorm -> bf16 ----------------
__global__ __launch_bounds__(256)
void k_rmsnorm_bf16(const float* __restrict__ x, const float* __restrict__ w,
                    u16* __restrict__ out) {
    int r = blockIdx.x;
    const float* row = x + (size_t)r * DM;
    int c0 = threadIdx.x * 3;
    float v[3]; float ss = 0.f;
#pragma unroll
    for (int i = 0; i < 3; ++i) { v[i] = row[c0 + i]; ss += v[i] * v[i]; }
#pragma unroll
    for (int o = 32; o > 0; o >>= 1) ss += __shfl_down(ss, o);
    __shared__ float s[4];
    int lane = threadIdx.x & 63, wv = threadIdx.x >> 6;
    if (lane == 0) s[wv] = ss;
    __syncthreads();
    float sc = rsqrtf((s[0] + s[1] + s[2] + s[3]) / (float)DM + EPSR);
#pragma unroll
    for (int i = 0; i < 3; ++i)
        out[(size_t)r * DM + c0 + i] = f2bf(v[i] * sc * w[c0 + i]);
}

// -------- fused multi-segment f32 -> bf16 weight conversion (one launch) --------
struct CvtSeg { const float* src; u16* dst; int sr, sc, sld, dc, blk0, total4; };
struct CvtArgs { CvtSeg seg[9]; };

__global__ __launch_bounds__(256)
void k_cvt_multi(CvtArgs a) {
    int b = blockIdx.x;
    int s = 0;
#pragma unroll
    for (int q = 1; q < 9; ++q) if (a.seg[q].blk0 <= b) s = q;
    const CvtSeg& g = a.seg[s];
    long i4 = (long)(b - g.blk0) * 256 + threadIdx.x;
    if (i4 >= g.total4) return;
    long i = i4 * 4;
    int r = (int)(i / g.dc), c0 = (int)(i % g.dc);
    us4 o;
#pragma unroll
    for (int e = 0; e < 4; ++e) {
        int c = c0 + e;
        float v = (r < g.sr && c < g.sc) ? g.src[(size_t)r * g.sld + c] : 0.f;
        o[e] = f2bf(v);
    }
    *(us4*)&g.dst[i] = o;
}

// -------- LDS-tiled causal depthwise conv (width 4) + bias + silu -> bf16 --------
// block: 256 d-channels x 16 rows; stages 19 input rows once (vs 4x global re-read).
// Boundary audit: tap j (weight w_j) applies to row r-3+j and is live iff l-3+j >= 0
// where l = r & (SL-1); guards below replicate that exactly (incl. batch seam).
__global__ __launch_bounds__(256)
void k_conv_silu_t(const float* __restrict__ xz, const float* __restrict__ cw,
                   const float* __restrict__ cb, u16* __restrict__ ucb) {
    __shared__ float su[19][256];
    int d0 = (blockIdx.x % 6) * 256;
    int r0 = (blockIdx.x / 6) * 16;
    int tid = threadIdx.x;
    int d = d0 + tid;
#pragma unroll
    for (int i = 0; i < 19; ++i) {
        int rr = r0 - 3 + i; rr = rr < 0 ? 0 : rr;      // clamped rows are never used
        su[i][tid] = xz[(size_t)rr * (2 * DI) + d];
    }
    __syncthreads();
    float w0 = cw[d * 4], w1 = cw[d * 4 + 1], w2 = cw[d * 4 + 2], w3 = cw[d * 4 + 3];
    float bia = cb[d];
#pragma unroll
    for (int i = 0; i < 16; ++i) {
        int r = r0 + i, l = r & (SL - 1);
        float acc = bia + su[i + 3][tid] * w3;          // j=3 always live (l>=0)
        if (l >= 3) acc += su[i][tid] * w0;
        if (l >= 2) acc += su[i + 1][tid] * w1;
        if (l >= 1) acc += su[i + 2][tid] * w2;
        float sv = acc / (1.f + __expf(-acc));
        ucb[(size_t)r * DI + d] = f2bf(sv);
    }
}

// ------ split-K reduce for x_proj: part[2048][8*128] -> xdbl f32 + xdblb bf16 ------
__global__ __launch_bounds__(256)
void k_xp_red(const float* __restrict__ part, float* __restrict__ xdbl,
              u16* __restrict__ xdblb) {
    int idx = blockIdx.x * 256 + threadIdx.x;    // 2048*128
    int row = idx >> 7, col = idx & 127;
    const float* p = part + (size_t)row * 1024 + col;
    float s = 0.f;
#pragma unroll
    for (int k = 0; k < 8; ++k) s += p[k * 128];
    xdbl[(size_t)row * 128 + col] = s;
    if (col < 64) xdblb[(size_t)row * 64 + col] = f2bf(s);
}

// ---------------- chunked selective scan (8 chunks x 128 steps, 1 kernel) --------------
__global__ __launch_bounds__(512)
void k_scan2(const float* __restrict__ delta, const u16* __restrict__ ucb,
             const float* __restrict__ xdbl, const float* __restrict__ xz,
             const float* __restrict__ alog, const float* __restrict__ Dp,
             u16* __restrict__ ybf) {
    __shared__ float ds2[8][16][20], us2[8][16][20], bn2[8][16][20], cn2[8][16][20];
    __shared__ float Sm[8][16][16], Pm[8][16][16];
    int b  = blockIdx.x / 96;
    int d0 = (blockIdx.x % 96) * 16;
    int tid = threadIdx.x, w = tid >> 6, lane = tid & 63;
    int ch = lane >> 2, nq = lane & 3;
    int d = d0 + ch;
    float A[4];
#pragma unroll
    for (int k = 0; k < 4; ++k) A[k] = -__expf(alog[d * DSN + nq + 4 * k]);
    int tb = w * 128;

    // ---- phase 1 ----
    float h[4] = {0.f, 0.f, 0.f, 0.f};
    float sdl = 0.f;
    for (int t0 = 0; t0 < 128; t0 += 16) {
        int row0 = b * SL + tb + t0;
#pragma unroll
        for (int i = 0; i < 4; ++i) {
            int lin = i * 64 + lane, tt = lin >> 4, cc = lin & 15;
            size_t row = (size_t)(row0 + tt);
            ds2[w][cc][tt] = delta[row * DI + d0 + cc];
            us2[w][cc][tt] = bf2f(ucb[row * DI + d0 + cc]);
            bn2[w][cc][tt] = xdbl[row * 128 + 48 + cc];
        }
#pragma unroll
        for (int g4 = 0; g4 < 4; ++g4) {
            f32x4 dl = *(const f32x4*)&ds2[w][ch][g4 * 4];
            f32x4 uv = *(const f32x4*)&us2[w][ch][g4 * 4];
            f32x4 bv[4];
#pragma unroll
            for (int k = 0; k < 4; ++k) bv[k] = *(const f32x4*)&bn2[w][nq + 4 * k][g4 * 4];
#pragma unroll
            for (int s = 0; s < 4; ++s) {
                float du = dl[s] * uv[s];
                sdl += dl[s];
#pragma unroll
                for (int k = 0; k < 4; ++k) {
                    float dA = __expf(dl[s] * A[k]);
                    h[k] = h[k] * dA + du * bv[k][s];
                }
            }
        }
    }
#pragma unroll
    for (int k = 0; k < 4; ++k) {
        Sm[w][ch][nq + 4 * k] = h[k];
        Pm[w][ch][nq + 4 * k] = __expf(A[k] * sdl);
    }
    __syncthreads();
    if (tid < 256) {
        int c2 = tid >> 4, n2 = tid & 15;
        float H = 0.f;
#pragma unroll
        for (int g = 0; g < 8; ++g) {
            float hi = H;
            H = Pm[g][c2][n2] * H + Sm[g][c2][n2];
            Sm[g][c2][n2] = hi;
        }
    }
    __syncthreads();
    // ---- phase 3 ----
    float Dv = Dp[d];
#pragma unroll
    for (int k = 0; k < 4; ++k) h[k] = Sm[w][ch][nq + 4 * k];
    for (int t0 = 0; t0 < 128; t0 += 16) {
        int row0 = b * SL + tb + t0;
#pragma unroll
        for (int i = 0; i < 4; ++i) {
            int lin = i * 64 + lane, tt = lin >> 4, cc = lin & 15;
            size_t row = (size_t)(row0 + tt);
            ds2[w][cc][tt] = delta[row * DI + d0 + cc];
            us2[w][cc][tt] = bf2f(ucb[row * DI + d0 + cc]);
            bn2[w][cc][tt] = xdbl[row * 128 + 48 + cc];
            cn2[w][cc][tt] = xdbl[row * 128 + 64 + cc];
        }
#pragma unroll
        for (int g4 = 0; g4 < 4; ++g4) {
            f32x4 dl = *(const f32x4*)&ds2[w][ch][g4 * 4];
            f32x4 uv = *(const f32x4*)&us2[w][ch][g4 * 4];
            f32x4 bv[4], cv[4];
#pragma unroll
            for (int k = 0; k < 4; ++k) {
                bv[k] = *(const f32x4*)&bn2[w][nq + 4 * k][g4 * 4];
                cv[k] = *(const f32x4*)&cn2[w][nq + 4 * k][g4 * 4];
            }
#pragma unroll
            for (int s = 0; s < 4; ++s) {
                float du = dl[s] * uv[s];
                float p = 0.f;
#pragma unroll
                for (int k = 0; k < 4; ++k) {
                    float dA = __expf(dl[s] * A[k]);
                    h[k] = h[k] * dA + du * bv[k][s];
                    p += h[k] * cv[k][s];
                }
                p += __shfl_xor(p, 1);
                p += __shfl_xor(p, 2);
                if (nq == 0) {
                    size_t row = (size_t)(row0 + g4 * 4 + s);
                    float z = xz[row * (2 * DI) + DI + d];
                    float y = p + uv[s] * Dv;
                    y *= z / (1.f + __expf(-z));
                    ybf[row * DI + d] = f2bf(y);
                }
            }
        }
    }
}

// ------- 128^2 bf16 MFMA GEMM (layer GEMMs), fused epilogue, optional split-K ------
// EPIL: 0 = plain, 1 = add residual, 2 = softplus(v + bias[col])
// SPLITK: wg/nTm selects a K-slice; C cols offset by slice*128 (ldc = nslices*128).
template <int EPIL, bool SPLITK>
__global__ __launch_bounds__(256)
void k_gemm_bt(const u16* __restrict__ A, const u16* __restrict__ W,
               float* C, const float* RES,
               const float* __restrict__ BIASV,
               int K, int ldk, int ldc, int nTm) {
    __shared__ u16 Al[128 * 32];
    __shared__ u16 Wl[128 * 32];
    int nwg = gridDim.x;
    int qc = nwg >> 3, rc = nwg & 7;
    int xcd = blockIdx.x & 7, j = blockIdx.x >> 3;
    int wg = (xcd < rc ? xcd * (qc + 1) : rc * (qc + 1) + (xcd - rc) * qc) + j;
    int m0 = (wg % nTm) * 128;
    int sl = wg / nTm;
    int n0 = SPLITK ? 0 : sl * 128;        // W row base
    int cb = SPLITK ? sl * 128 : n0;       // C col base
    int kb = SPLITK ? sl * K : 0;          // K slice base

    int tid = threadIdx.x, wave = tid >> 6, lane = tid & 63;
    int wm = wave >> 1, wn = wave & 1;
    f32x4 acc[4][4] = {};
    const int rS = (lane >> 2);
    const int kS = (((lane & 3) ^ ((lane >> 3) & 3)) * 8);
    const int kofs = (((lane >> 4) ^ ((lane >> 1) & 3)) * 8);
    const int fr = lane & 15;

    for (int k0 = 0; k0 < K; k0 += 32) {
#pragma unroll
        for (int i = 0; i < 2; ++i) {
            int rowA = m0 + wave * 32 + i * 16 + rS;
            G_LDS16(A + (size_t)rowA * ldk + kb + k0 + kS, &Al[wave * 1024 + i * 512]);
            int rowW = n0 + wave * 32 + i * 16 + rS;
            G_LDS16(W + (size_t)rowW * ldk + kb + k0 + kS, &Wl[wave * 1024 + i * 512]);
        }
        __syncthreads();
        short8 af[4], bfr[4];
#pragma unroll
        for (int f = 0; f < 4; ++f) {
            af[f]  = *(const short8*)&Al[(wm * 64 + f * 16 + fr) * 32 + kofs];
            bfr[f] = *(const short8*)&Wl[(wn * 64 + f * 16 + fr) * 32 + kofs];
        }
#pragma unroll
        for (int i = 0; i < 4; ++i)
#pragma unroll
            for (int jj = 0; jj < 4; ++jj)
                acc[i][jj] = __builtin_amdgcn_mfma_f32_16x16x32_bf16(af[i], bfr[jj], acc[i][jj], 0, 0, 0);
        __syncthreads();
    }
    int r4 = (lane >> 4) * 4;
#pragma unroll
    for (int i = 0; i < 4; ++i)
#pragma unroll
        for (int jj = 0; jj < 4; ++jj) {
            int col = cb + wn * 64 + jj * 16 + fr;
            float bia = (EPIL == 2) ? BIASV[col] : 0.f;
#pragma unroll
            for (int rr = 0; rr < 4; ++rr) {
                int row = m0 + wm * 64 + i * 16 + r4 + rr;
                size_t off = (size_t)row * ldc + col;
                float v = acc[i][jj][rr];
                if (EPIL == 1) v += RES[off];
                if (EPIL == 2) { v += bia; v = (v > 20.f) ? v : log1pf(__expf(v)); }
                C[off] = v;
            }
        }
}

// ===== 256^2 bf16 GEMM (lm_head): 3-buffer race-free pipeline, BK=32, 96 KiB LDS =====
// Plateaued at ~238 us across 4 structural variants (conflicts/LDS/barriers/depth all
// ruled out); keep this race-free form. launch_bounds MUST stay (512,2) (r11 spill).
#define BAR  __builtin_amdgcn_s_barrier()
#define LGK0 do { asm volatile("s_waitcnt lgkmcnt(0)" ::: "memory"); \
                  __builtin_amdgcn_sched_barrier(0); } while (0)
#define VMC4 asm volatile("s_waitcnt vmcnt(4)" ::: "memory")
#define VMC0 asm volatile("s_waitcnt vmcnt(0)" ::: "memory")

#define STG(t, b, op, half, GB, RB) do {                                       \
    const u16* _g = (GB) + (size_t)((RB) + (half) * 128 + (w << 4) + srow) * K \
                    + (t) * 32 + scol;                                         \
    G_LDS16(_g, &lds[b][op][half][w << 9]);                                    \
} while (0)

#define RDA(dst, b, mq) do {                                                   \
    _Pragma("unroll") for (int _m = 0; _m < 4; ++_m)                           \
        dst[_m] = *(const short8*)&lds[b][0][wm]                               \
            [((mq) * 64 + _m * 16 + fr) * 32 + rd_sw];                         \
} while (0)

#define RDB(b, nq) do {                                                       \
    _Pragma("unroll") for (int _n = 0; _n < 2; ++_n)                           \
        bfv[_n] = *(const short8*)&lds[b][1][wbh]                              \
            [(wbr * 64 + (nq) * 32 + _n * 16 + fr) * 32 + rd_sw];              \
} while (0)

#define MM8(AF, mq, nq) do {                                                  \
    __builtin_amdgcn_s_setprio(1);                                            \
    _Pragma("unroll") for (int _m = 0; _m < 4; ++_m)                           \
    _Pragma("unroll") for (int _n = 0; _n < 2; ++_n)                           \
        acc[(mq) * 4 + _m][(nq) * 2 + _n] =                                    \
            __builtin_amdgcn_mfma_f32_16x16x32_bf16(                           \
                AF[_m], bfv[_n], acc[(mq) * 4 + _m][(nq) * 2 + _n], 0, 0, 0);  \
    __builtin_amdgcn_s_setprio(0);                                            \
} while (0)

#define TILE(t, bR, bS, STAGE_ON, WAIT) do {                                   \
    RDA(af0, bR, 0); RDA(af1, bR, 1); RDB(bR, 0);                              \
    if (STAGE_ON) { STG((t) + 2, bS, 0, 0, Ap, m0);                            \
                    STG((t) + 2, bS, 0, 1, Ap, m0); }                          \
    BAR; LGK0; MM8(af0, 0, 0); MM8(af1, 1, 0); BAR;                            \
    RDB(bR, 1);                                                                \
    if (STAGE_ON) { STG((t) + 2, bS, 1, 0, Wp, n0);                            \
                    STG((t) + 2, bS, 1, 1, Wp, n0); }                          \
    BAR; LGK0; MM8(af1, 1, 1); MM8(af0, 0, 1);                                 \
    if ((WAIT) == 0) { VMC4; } else if ((WAIT) == 1) { VMC0; }                 \
    BAR;                                                                       \
} while (0)

template <int K>
__global__ __launch_bounds__(512, 2)
void k_gemm256(const u16* __restrict__ Ap, const u16* __restrict__ Wp,
               float* __restrict__ C, int ldc, int nmax, int nTm) {
    constexpr int NT = K / 32;
    static_assert(NT % 3 == 0 && NT >= 6, "NT must be a multiple of 3");
    __shared__ __align__(16) u16 lds[3][2][2][4096];

    int per8 = gridDim.x >> 3;
    int wg = (blockIdx.x & 7) * per8 + (blockIdx.x >> 3);
    int m0 = (wg % nTm) * 256, n0 = (wg / nTm) * 256;

    int tid = threadIdx.x, w = tid >> 6, lane = tid & 63;
    int wm = w >> 2, wn = w & 3, wbh = wn >> 1, wbr = wn & 1;
    int fr = lane & 15;
    int rd_sw = (((lane >> 4) ^ ((lane >> 1) & 3)) * 8);
    int srow  = lane >> 2;
    int scol  = (((lane & 3) ^ ((lane >> 3) & 3)) * 8);

    f32x4 acc[8][4] = {};
    short8 af0[4], af1[4], bfv[2];

    STG(0, 0, 0, 0, Ap, m0); STG(0, 0, 0, 1, Ap, m0);
    STG(0, 0, 1, 0, Wp, n0); STG(0, 0, 1, 1, Wp, n0);
    STG(1, 1, 0, 0, Ap, m0); STG(1, 1, 0, 1, Ap, m0);
    STG(1, 1, 1, 0, Wp, n0); STG(1, 1, 1, 1, Wp, n0);
    VMC4; BAR;

    for (int j = 0; j < NT / 3 - 1; ++j) {
        const int t0 = 3 * j;
        TILE(t0,     0, 2, 1, 0);
        TILE(t0 + 1, 1, 0, 1, 0);
        TILE(t0 + 2, 2, 1, 1, 0);
    }
    TILE(NT - 3, 0, 2, 1, 0);
    TILE(NT - 2, 1, 0, 0, 1);
    TILE(NT - 1, 2, 0, 0, 2);

    int r4 = (lane >> 4) * 4;
#pragma unroll
    for (int mi = 0; mi < 8; ++mi)
#pragma unroll
        for (int ni = 0; ni < 4; ++ni) {
            int col = n0 + wn * 64 + (ni >> 1) * 32 + (ni & 1) * 16 + fr;
            if (col >= nmax) continue;
            int row = m0 + wm * 128 + (mi >> 2) * 64 + (mi & 3) * 16 + r4;
#pragma unroll
            for (int rr = 0; rr < 4; ++rr)
                C[(size_t)(row + rr) * ldc + col] = acc[mi][ni][rr];
        }
}

// ---------------- host ----------------
extern "C" void kernel_launch(void* const* d_in, const int* in_sizes, int n_in,
                              void* d_out, int out_size, void* d_ws, size_t ws_size,
                              hipStream_t stream) {
    (void)in_sizes; (void)n_in; (void)out_size;
    const int*   tok   = (const int*)d_in[0];
    const float* emb   = (const float*)d_in[1];
    const float* normw = (const float*)d_in[2];
    const float* inw   = (const float*)d_in[3];
    const float* cw    = (const float*)d_in[4];
    const float* cb    = (const float*)d_in[5];
    const float* xpw   = (const float*)d_in[6];
    const float* dtw   = (const float*)d_in[7];
    const float* dtb   = (const float*)d_in[8];
    const float* alog  = (const float*)d_in[9];
    const float* Dp    = (const float*)d_in[10];
    const float* outw  = (const float*)d_in[11];
    const float* normf = (const float*)d_in[12];
    const float* lmw   = (const float*)d_in[13];
    float* out = (float*)d_out;

    char* p = (char*)d_ws;
    auto alloc = [&](size_t bytes) { char* r = p; p += (bytes + 255) & ~(size_t)255; return r; };
    float* x     = (float*)alloc((size_t)MROWS * DM * 4);
    u16*   xnb   = (u16*)  alloc((size_t)MROWS * DM * 2);
    float* xz    = (float*)alloc((size_t)MROWS * 2 * DI * 4);
    u16*   ucb   = (u16*)  alloc((size_t)MROWS * DI * 2);
    float* xdbl  = (float*)alloc((size_t)MROWS * 128 * 4);
    u16*   xdblb = (u16*)  alloc((size_t)MROWS * 64 * 2);
    float* part  = (float*)alloc((size_t)MROWS * 1024 * 4);   // x_proj split-K partials
    float* delta = (float*)alloc((size_t)MROWS * DI * 4);
    u16*   ybf   = (u16*)  alloc((size_t)MROWS * DI * 2);
    u16*   winb  = (u16*)  alloc((size_t)NB * (2 * DI) * DM * 2);
    u16*   wxpb  = (u16*)  alloc((size_t)NB * 128 * DI * 2);
    u16*   wdtb  = (u16*)  alloc((size_t)NB * DI * 64 * 2);
    u16*   woutb = (u16*)  alloc((size_t)NB * DM * DI * 2);
    u16*   wlmb  = (u16*)  alloc((size_t)VOCP * DM * 2);
    if ((size_t)(p - (char*)d_ws) > ws_size) return;  // insufficient scratch: fail loudly

    // ---- one fused weight-conversion launch (9 segments) ----
    CvtArgs ca;
    int blk = 0;
    auto seg = [&](int idx, const float* s, u16* d, int sr, int sc, int sld, int dc, int dr) {
        int t4 = dr * dc / 4;
        ca.seg[idx] = CvtSeg{s, d, sr, sc, sld, dc, blk, t4};
        blk += (t4 + 255) / 256;
    };
    seg(0, lmw, wlmb, VOC, DM, DM, DM, VOCP);
    seg(1, inw,                          winb,                          2 * DI, DM, DM, DM, 2 * DI);
    seg(2, inw + (size_t)2 * DI * DM,    winb + (size_t)2 * DI * DM,    2 * DI, DM, DM, DM, 2 * DI);
    seg(3, xpw,                          wxpb,                          80, DI, DI, DI, 128);
    seg(4, xpw + (size_t)80 * DI,        wxpb + (size_t)128 * DI,       80, DI, DI, DI, 128);
    seg(5, dtw,                          wdtb,                          DI, 48, 48, 64, DI);
    seg(6, dtw + (size_t)DI * 48,        wdtb + (size_t)DI * 64,        DI, 48, 48, 64, DI);
    seg(7, outw,                         woutb,                         DM, DI, DI, DI, DM);
    seg(8, outw + (size_t)DM * DI,       woutb + (size_t)DM * DI,       DM, DI, DI, DI, DM);
    k_cvt_multi<<<dim3(blk), 256, 0, stream>>>(ca);

    // embedding + layer-0 rmsnorm fused
    k_embed_rms<<<MROWS, 256, 0, stream>>>(tok, emb, normw, x, xnb);

    for (int i = 0; i < NB; ++i) {
        if (i > 0)
            k_rmsnorm_bf16<<<MROWS, 256, 0, stream>>>(x, normw + i * DM, xnb);

        k_gemm_bt<0, false><<<dim3(16 * (2 * DI / 128)), 256, 0, stream>>>(
            xnb, winb + (size_t)i * 2 * DI * DM, xz, nullptr, nullptr,
            DM, DM, 2 * DI, 16);

        // LDS-tiled conv + silu -> bf16 only (f32 uc buffer eliminated)
        k_conv_silu_t<<<dim3(6 * (MROWS / 16)), 256, 0, stream>>>(
            xz, cw + (size_t)i * DI * 4, cb + (size_t)i * DI, ucb);

        // x_proj (N=128) split-K x8: 128 blocks, partials [2048][8*128]
        k_gemm_bt<0, true><<<dim3(16 * 8), 256, 0, stream>>>(
            ucb, wxpb + (size_t)i * 128 * DI, part, nullptr, nullptr,
            DI / 8, DI, 1024, 16);
        k_xp_red<<<dim3(MROWS * 128 / 256), 256, 0, stream>>>(part, xdbl, xdblb);

        // dt GEMM (K=64) with fused softplus(v + dt_bias) -> delta
        k_gemm_bt<2, false><<<dim3(16 * (DI / 128)), 256, 0, stream>>>(
            xdblb, wdtb + (size_t)i * DI * 64, delta, nullptr, dtb + (size_t)i * DI,
            64, 64, DI, 16);

        k_scan2<<<dim3(NB * (DI / 16)), 512, 0, stream>>>(
            delta, ucb, xdbl, xz, alog + (size_t)i * DI * DSN, Dp + i * DI, ybf);

        // out_proj (N=768) with fused residual add
        k_gemm_bt<1, false><<<dim3(16 * (DM / 128)), 256, 0, stream>>>(
            ybf, woutb + (size_t)i * DM * DI, x, x, nullptr, DI, DI, DM, 16);
    }

    k_rmsnorm_bf16<<<MROWS, 256, 0, stream>>>(x, normf, xnb);
    k_gemm256<DM><<<dim3(8 * (VOCP / 256)), 512, 0, stream>>>(
        xnb, wlmb, out, VOC, VOC, 8);
}